// Round 1
// baseline (13361.244 us; speedup 1.0000x reference)
//
#include <hip/hip_runtime.h>
#include <math.h>

#define DEV __device__ __forceinline__

namespace {
constexpr int B_ = 4, T_ = 8, N_ = 3000, E_ = 12000;
constexpr int OUTS_ = 45001;  // per-batch output stride: N*7 + E + E + 1
}

DEV float sigm_(float x) { return 1.0f / (1.0f + expf(-x)); }
DEV float softplus_(float x) { return fmaxf(x, 0.0f) + log1pf(expf(-fabsf(x))); }
// order-preserving float<->uint encoding for atomicMax on floats
DEV unsigned fenc_(float f) {
  unsigned u = __float_as_uint(f);
  return (u & 0x80000000u) ? ~u : (u | 0x80000000u);
}
DEV float fdec_(unsigned u) {
  return (u & 0x80000000u) ? __uint_as_float(u ^ 0x80000000u) : __uint_as_float(~u);
}
DEV float wred_(float v) {
  #pragma unroll
  for (int o = 32; o > 0; o >>= 1) v += __shfl_xor(v, o, 64);
  return v;
}

// ---------------------------------------------------------------------------
// Generic fp32 GEMM: C[M,N] = A[M,K] @ W[K,N] (+bias) (+C if flags&1) (relu if flags&2)
// A row stride = lda. Optional logical-row remap (for fused_seq time slicing):
//   physical_row = (r/mDiv)*mOuter + mOff + r%mDiv   (mDiv==0 -> identity)
// ---------------------------------------------------------------------------
__global__ __launch_bounds__(256) void gemm_k(
    const float* __restrict__ A, const float* __restrict__ W,
    const float* __restrict__ bias, float* __restrict__ C,
    int M, int N, int K, int lda, int flags,
    int mDiv, int mOuter, int mOff)
{
  __shared__ float As[16][68];   // [k][m], padded
  __shared__ float Ws[16][64];   // [k][n]
  const int tid = threadIdx.x;
  const int bm = blockIdx.y * 64;
  const int bn = blockIdx.x * 64;
  const int tx = tid & 15;       // -> n
  const int ty = tid >> 4;       // -> m
  const int ar = tid >> 2;            // A tile row (0..63)
  const int ac = (tid & 3) << 2;      // A tile col (0,4,8,12)
  const int wr = tid >> 4;            // W tile row (0..15)
  const int wc = (tid & 15) << 2;     // W tile col (0..60)
  const int grow = bm + ar;
  const float* Arow = nullptr;
  if (grow < M) {
    int r = grow;
    if (mDiv > 0) r = (grow / mDiv) * mOuter + mOff + (grow % mDiv);
    Arow = A + (size_t)r * lda;
  }
  float acc[4][4] = {};
  for (int k0 = 0; k0 < K; k0 += 16) {
    float4 av = make_float4(0.f, 0.f, 0.f, 0.f);
    if (Arow) {
      if (k0 + ac + 3 < K) {
        av = *(const float4*)(Arow + k0 + ac);
      } else {
        av.x = (k0 + ac + 0 < K) ? Arow[k0 + ac + 0] : 0.f;
        av.y = (k0 + ac + 1 < K) ? Arow[k0 + ac + 1] : 0.f;
        av.z = (k0 + ac + 2 < K) ? Arow[k0 + ac + 2] : 0.f;
        av.w = (k0 + ac + 3 < K) ? Arow[k0 + ac + 3] : 0.f;
      }
    }
    As[ac + 0][ar] = av.x;
    As[ac + 1][ar] = av.y;
    As[ac + 2][ar] = av.z;
    As[ac + 3][ar] = av.w;
    float4 wv = make_float4(0.f, 0.f, 0.f, 0.f);
    if (k0 + wr < K) {
      const int gc = bn + wc;
      const float* wp = W + (size_t)(k0 + wr) * N + gc;
      if (gc + 3 < N) {
        wv = *(const float4*)wp;
      } else {
        wv.x = (gc + 0 < N) ? wp[0] : 0.f;
        wv.y = (gc + 1 < N) ? wp[1] : 0.f;
        wv.z = (gc + 2 < N) ? wp[2] : 0.f;
        wv.w = (gc + 3 < N) ? wp[3] : 0.f;
      }
    }
    *(float4*)&Ws[wr][wc] = wv;
    __syncthreads();
    #pragma unroll
    for (int kk = 0; kk < 16; ++kk) {
      const float4 a = *(const float4*)&As[kk][ty << 2];
      const float4 b = *(const float4*)&Ws[kk][tx << 2];
      acc[0][0] += a.x * b.x; acc[0][1] += a.x * b.y; acc[0][2] += a.x * b.z; acc[0][3] += a.x * b.w;
      acc[1][0] += a.y * b.x; acc[1][1] += a.y * b.y; acc[1][2] += a.y * b.z; acc[1][3] += a.y * b.w;
      acc[2][0] += a.z * b.x; acc[2][1] += a.z * b.y; acc[2][2] += a.z * b.z; acc[2][3] += a.z * b.w;
      acc[3][0] += a.w * b.x; acc[3][1] += a.w * b.y; acc[3][2] += a.w * b.z; acc[3][3] += a.w * b.w;
    }
    __syncthreads();
  }
  #pragma unroll
  for (int i = 0; i < 4; ++i) {
    const int row = bm + (ty << 2) + i;
    if (row >= M) continue;
    float* crow = C + (size_t)row * N;
    #pragma unroll
    for (int j = 0; j < 4; ++j) {
      const int col = bn + (tx << 2) + j;
      if (col >= N) continue;
      float v = acc[i][j];
      if (bias) v += bias[col];
      if (flags & 1) v += crow[col];
      if (flags & 2) v = fmaxf(v, 0.f);
      crow[col] = v;
    }
  }
}

// ---------------------------------------------------------------------------
// Stage A kernels
// ---------------------------------------------------------------------------
// Gather tokens for one batch b: tok[(t*N+n)*3+s][0:256] = inp_s[b,t,n,:]
__global__ void gather_tok_k(const float* __restrict__ env,
                             const float* __restrict__ infra,
                             const float* __restrict__ robot,
                             float* __restrict__ tok, int b)
{
  const int idx = blockIdx.x * blockDim.x + threadIdx.x;  // float4 units
  const int total4 = T_ * N_ * 3 * 64;
  if (idx >= total4) return;
  const int flat = idx << 2;
  const int d = flat & 255;
  const int rs = flat >> 8;
  const int s = rs % 3;
  const int tn = rs / 3;
  const float* srcp = (s == 0 ? env : (s == 1 ? infra : robot));
  const float4 v = *(const float4*)(srcp + ((size_t)b * T_ * N_ + tn) * 256 + d);
  *(float4*)(tok + (size_t)flat) = v;
}

// per-(node,head) 3x3 attention; writes O in-place into the Q slots of qkv
__global__ void attn_k(float* __restrict__ qkv, int nodes)
{
  const int idx = blockIdx.x * blockDim.x + threadIdx.x;
  if (idx >= nodes * 8) return;
  const int node = idx >> 3, h = idx & 7;
  float* base = qkv + (size_t)node * 2304 + h * 32;
  float att[3][3];
  #pragma unroll
  for (int s = 0; s < 3; ++s) {
    const float* q = base + s * 768;
    #pragma unroll
    for (int t = 0; t < 3; ++t) {
      const float* k = base + t * 768 + 256;
      float d = 0.f;
      #pragma unroll
      for (int i = 0; i < 32; i += 4) {
        const float4 qv = *(const float4*)(q + i);
        const float4 kv = *(const float4*)(k + i);
        d += qv.x * kv.x + qv.y * kv.y + qv.z * kv.z + qv.w * kv.w;
      }
      att[s][t] = d * 0.17677669529663687f;  // 1/sqrt(32)
    }
  }
  #pragma unroll
  for (int s = 0; s < 3; ++s) {
    const float m = fmaxf(att[s][0], fmaxf(att[s][1], att[s][2]));
    const float e0 = expf(att[s][0] - m);
    const float e1 = expf(att[s][1] - m);
    const float e2 = expf(att[s][2] - m);
    const float inv = 1.f / (e0 + e1 + e2);
    att[s][0] = e0 * inv; att[s][1] = e1 * inv; att[s][2] = e2 * inv;
  }
  #pragma unroll
  for (int s = 0; s < 3; ++s) {
    float o[32];
    #pragma unroll
    for (int i = 0; i < 32; ++i) o[i] = 0.f;
    #pragma unroll
    for (int t = 0; t < 3; ++t) {
      const float* v = base + t * 768 + 512;
      const float w = att[s][t];
      #pragma unroll
      for (int i = 0; i < 32; ++i) o[i] += w * v[i];
    }
    float* op = base + s * 768;  // overwrite own q slot
    #pragma unroll
    for (int i = 0; i < 32; i += 4)
      *(float4*)(op + i) = make_float4(o[i], o[i + 1], o[i + 2], o[i + 3]);
  }
}

// mean over the 3 token rows + LayerNorm -> fused_seq row. 1 wave per node.
__global__ __launch_bounds__(64) void meanln_k(
    const float* __restrict__ OW, const float* __restrict__ g,
    const float* __restrict__ bta, float* __restrict__ outp)
{
  const int row = blockIdx.x;
  const int d0 = threadIdx.x << 2;
  const float* r0 = OW + (size_t)row * 768;
  const float4 a = *(const float4*)(r0 + d0);
  const float4 b4 = *(const float4*)(r0 + 256 + d0);
  const float4 c4 = *(const float4*)(r0 + 512 + d0);
  float x[4];
  x[0] = (a.x + b4.x + c4.x) * (1.f / 3.f);
  x[1] = (a.y + b4.y + c4.y) * (1.f / 3.f);
  x[2] = (a.z + b4.z + c4.z) * (1.f / 3.f);
  x[3] = (a.w + b4.w + c4.w) * (1.f / 3.f);
  float s = x[0] + x[1] + x[2] + x[3];
  s = wred_(s);
  const float mean = s * (1.f / 256.f);
  float vs = 0.f;
  #pragma unroll
  for (int i = 0; i < 4; ++i) { const float dd = x[i] - mean; vs += dd * dd; }
  vs = wred_(vs);
  const float inv = 1.0f / sqrtf(vs * (1.f / 256.f) + 1e-5f);
  const float4 gv = *(const float4*)(g + d0);
  const float4 bv = *(const float4*)(bta + d0);
  float4 o;
  o.x = (x[0] - mean) * inv * gv.x + bv.x;
  o.y = (x[1] - mean) * inv * gv.y + bv.y;
  o.z = (x[2] - mean) * inv * gv.z + bv.z;
  o.w = (x[3] - mean) * inv * gv.w + bv.w;
  *(float4*)(outp + (size_t)row * 256 + d0) = o;
}

// ---------------------------------------------------------------------------
// GAT kernels
// ---------------------------------------------------------------------------
// per (row,h): dot32 with a_src and a_dst
__global__ void alphas_k(const float* __restrict__ xw, const float* __restrict__ as,
                         const float* __restrict__ ad, float* __restrict__ sal,
                         float* __restrict__ dal, int rows)
{
  const int idx = blockIdx.x * blockDim.x + threadIdx.x;
  if (idx >= rows * 8) return;
  const int row = idx >> 3, h = idx & 7;
  const float* x = xw + (size_t)row * 256 + h * 32;
  const float* a1 = as + h * 32;
  const float* a2 = ad + h * 32;
  float s = 0.f, d = 0.f;
  #pragma unroll
  for (int i = 0; i < 32; ++i) { s += x[i] * a1[i]; d += x[i] * a2[i]; }
  sal[idx] = s; dal[idx] = d;
}

// per (row,h): dot32 with a_edge
__global__ void elog_k(const float* __restrict__ ew, const float* __restrict__ ae,
                       float* __restrict__ el, int rows)
{
  const int idx = blockIdx.x * blockDim.x + threadIdx.x;
  if (idx >= rows * 8) return;
  const int row = idx >> 3, h = idx & 7;
  const float* x = ew + (size_t)row * 256 + h * 32;
  const float* a1 = ae + h * 32;
  float s = 0.f;
  #pragma unroll
  for (int i = 0; i < 32; ++i) s += x[i] * a1[i];
  el[idx] = s;
}

// logit = leaky(sal[src]+dal[dst]+elog); store + atomic segment max per (b,dst,h)
__global__ void logitmax_k(const float* __restrict__ sal, const float* __restrict__ dal,
                           const float* __restrict__ el, const int* __restrict__ src,
                           const int* __restrict__ dst, float* __restrict__ logbuf,
                           unsigned* __restrict__ mmax)
{
  const int idx = blockIdx.x * blockDim.x + threadIdx.x;
  if (idx >= B_ * E_ * 8) return;
  const int b = idx / (E_ * 8);
  const int r = idx - b * E_ * 8;
  const int e = r >> 3, h = r & 7;
  const int s = src[e], d = dst[e];
  float lg = sal[(b * N_ + s) * 8 + h] + dal[(b * N_ + d) * 8 + h] + el[idx];
  lg = lg > 0.f ? lg : 0.2f * lg;
  logbuf[idx] = lg;
  atomicMax(&mmax[(b * N_ + d) * 8 + h], fenc_(lg));
}

// e = exp(logit - max[dst]); store; atomic segment sum
__global__ void expsum_k(float* __restrict__ logbuf, const unsigned* __restrict__ mmax,
                         const int* __restrict__ dst, float* __restrict__ ssum)
{
  const int idx = blockIdx.x * blockDim.x + threadIdx.x;
  if (idx >= B_ * E_ * 8) return;
  const int b = idx / (E_ * 8);
  const int r = idx - b * E_ * 8;
  const int e = r >> 3, h = r & 7;
  const int d = dst[e];
  const float m = fdec_(mmax[(b * N_ + d) * 8 + h]);
  const float ex = expf(logbuf[idx] - m);
  logbuf[idx] = ex;
  atomicAdd(&ssum[(b * N_ + d) * 8 + h], ex);
}

// out[b,dst,h,:] += (xw[b,src,h,:] + ew[b,e,h,:]) * w
__global__ void scatter_k(const float* __restrict__ logbuf, const float* __restrict__ ssum,
                          const float* __restrict__ xw, const float* __restrict__ ew,
                          const int* __restrict__ src, const int* __restrict__ dst,
                          float* __restrict__ outp)
{
  const int idx = blockIdx.x * blockDim.x + threadIdx.x;
  if (idx >= B_ * E_ * 8) return;
  const int b = idx / (E_ * 8);
  const int r = idx - b * E_ * 8;
  const int e = r >> 3, h = r & 7;
  const int s = src[e], d = dst[e];
  const float w = logbuf[idx] / (ssum[(b * N_ + d) * 8 + h] + 1e-16f);
  const float* xs = xw + ((size_t)(b * N_ + s)) * 256 + h * 32;
  const float* ee = ew + ((size_t)(b * E_ + e)) * 256 + h * 32;
  float* op = outp + ((size_t)(b * N_ + d)) * 256 + h * 32;
  #pragma unroll
  for (int i = 0; i < 32; ++i) atomicAdd(op + i, (xs[i] + ee[i]) * w);
}

// LSTM cell pointwise. grid = B*N blocks, 256 threads (one per feature)
__global__ __launch_bounds__(256) void lstm_k(const float* __restrict__ gates,
                                              float* __restrict__ h, float* __restrict__ c)
{
  const int row = blockIdx.x;
  const int d = threadIdx.x;
  const float* g = gates + (size_t)row * 1024;
  const float i_ = sigm_(g[d]);
  const float f_ = sigm_(g[256 + d]);
  const float gg = tanhf(g[512 + d]);
  const float o_ = sigm_(g[768 + d]);
  const size_t idx = (size_t)row * 256 + d;
  const float cn = f_ * c[idx] + i_ * gg;
  c[idx] = cn;
  h[idx] = o_ * tanhf(cn);
}

// h = LayerNorm(h + add) with per-layer g,b. 1 wave per row.
__global__ __launch_bounds__(64) void resln_k(float* __restrict__ h,
                                              const float* __restrict__ add,
                                              const float* __restrict__ g,
                                              const float* __restrict__ bta)
{
  const int row = blockIdx.x;
  const int d0 = threadIdx.x << 2;
  float* hp = h + (size_t)row * 256;
  const float4 hv = *(const float4*)(hp + d0);
  const float4 av = *(const float4*)(add + (size_t)row * 256 + d0);
  float x[4] = { hv.x + av.x, hv.y + av.y, hv.z + av.z, hv.w + av.w };
  float s = x[0] + x[1] + x[2] + x[3];
  s = wred_(s);
  const float mean = s * (1.f / 256.f);
  float vs = 0.f;
  #pragma unroll
  for (int i = 0; i < 4; ++i) { const float dd = x[i] - mean; vs += dd * dd; }
  vs = wred_(vs);
  const float inv = 1.0f / sqrtf(vs * (1.f / 256.f) + 1e-5f);
  const float4 gv = *(const float4*)(g + d0);
  const float4 bv = *(const float4*)(bta + d0);
  float4 o;
  o.x = (x[0] - mean) * inv * gv.x + bv.x;
  o.y = (x[1] - mean) * inv * gv.y + bv.y;
  o.z = (x[2] - mean) * inv * gv.z + bv.z;
  o.w = (x[3] - mean) * inv * gv.w + bv.w;
  *(float4*)(hp + d0) = o;
}

// ---------------------------------------------------------------------------
// Head kernels
// ---------------------------------------------------------------------------
// node-head second layer: out[b,n,j] = act_j(hidden_j[row] . w2_j + b2_j)
__global__ void nh2_k(const float* __restrict__ hidden, const float* __restrict__ w2,
                      const float* __restrict__ b2, float* __restrict__ outp)
{
  const int idx = blockIdx.x * blockDim.x + threadIdx.x;
  if (idx >= B_ * N_ * 7) return;
  const int row = idx / 7, j = idx % 7;
  const float* hp = hidden + ((size_t)j * (B_ * N_) + row) * 64;
  const float* wp = w2 + j * 64;
  float a = 0.f;
  #pragma unroll
  for (int u = 0; u < 64; ++u) a += hp[u] * wp[u];
  a += b2[j];
  if (j == 0 || j == 6) a = sigm_(a);
  else if (j == 1) a = softplus_(a);
  const int b = row / N_, n = row % N_;
  outp[(size_t)b * OUTS_ + n * 7 + j] = a;
}

// h_global = mean over nodes
__global__ __launch_bounds__(256) void hglob_k(const float* __restrict__ h, float* __restrict__ hg)
{
  const int b = blockIdx.x;
  const int d = threadIdx.x;
  float s = 0.f;
  for (int n = 0; n < N_; ++n) s += h[((size_t)(b * N_ + n)) * 256 + d];
  hg[b * 256 + d] = s * (1.f / (float)N_);
}

// freq = mlp(h_global) (head 7), one wave per batch
__global__ __launch_bounds__(64) void freq_k(const float* __restrict__ hg,
                                             const float* __restrict__ w1, const float* __restrict__ b1,
                                             const float* __restrict__ w2, const float* __restrict__ b2,
                                             float* __restrict__ outp)
{
  const int b = blockIdx.x;
  const int u = threadIdx.x;
  float a = b1[u];
  for (int k = 0; k < 256; ++k) a += hg[b * 256 + k] * w1[k * 64 + u];
  a = fmaxf(a, 0.f) * w2[u];
  a = wred_(a);
  if (u == 0) outp[(size_t)b * OUTS_ + 45000] = a + b2[0];
}

// gather ef = [h[b,src], h[b,dst]] (B*E x 512)
__global__ void ef_k(const float* __restrict__ h, const int* __restrict__ src,
                     const int* __restrict__ dst, float* __restrict__ ef)
{
  const int idx = blockIdx.x * blockDim.x + threadIdx.x;  // float4 units
  if (idx >= B_ * E_ * 128) return;
  const int q = idx & 127;
  const int row = idx >> 7;
  const int b = row / E_, e = row % E_;
  const int d = q << 2;
  const float* p = (d < 256)
      ? h + ((size_t)(b * N_ + src[e])) * 256 + d
      : h + ((size_t)(b * N_ + dst[e])) * 256 + (d - 256);
  *(float4*)(ef + (size_t)row * 512 + d) = *(const float4*)p;
}

// edge-head second layer (no activation)
__global__ void eh2_k(const float* __restrict__ hidden, const float* __restrict__ w2,
                      const float* __restrict__ b2, float* __restrict__ outp)
{
  const int idx = blockIdx.x * blockDim.x + threadIdx.x;
  if (idx >= 2 * B_ * E_) return;
  const int jj = idx / (B_ * E_);
  const int r = idx - jj * (B_ * E_);
  const int b = r / E_, e = r % E_;
  const float* hp = hidden + ((size_t)jj * (B_ * E_) + r) * 64;
  const float* wp = w2 + jj * 64;
  float a = 0.f;
  #pragma unroll
  for (int u = 0; u < 64; ++u) a += hp[u] * wp[u];
  a += b2[jj];
  outp[(size_t)b * OUTS_ + 21000 + jj * 12000 + e] = a;
}

// ---------------------------------------------------------------------------
extern "C" void kernel_launch(void* const* d_in, const int* in_sizes, int n_in,
                              void* d_out, int out_size, void* d_ws, size_t ws_size,
                              hipStream_t stream)
{
  const float* env      = (const float*)d_in[0];
  const float* infra    = (const float*)d_in[1];
  const float* robot    = (const float*)d_in[2];
  const float* edgeattr = (const float*)d_in[3];
  const int*   eidx     = (const int*)d_in[4];
  const float* wqkv     = (const float*)d_in[5];
  const float* bqkv     = (const float*)d_in[6];
  const float* wo       = (const float*)d_in[7];
  const float* bo       = (const float*)d_in[8];
  const float* lnf_g    = (const float*)d_in[9];
  const float* lnf_b    = (const float*)d_in[10];
  const float* we_emb   = (const float*)d_in[11];
  const float* be_emb   = (const float*)d_in[12];
  const float* tg_W     = (const float*)d_in[13];
  const float* tg_We    = (const float*)d_in[14];
  const float* tg_asrc  = (const float*)d_in[15];
  const float* tg_adst  = (const float*)d_in[16];
  const float* tg_aedge = (const float*)d_in[17];
  const float* w_ih     = (const float*)d_in[18];
  const float* w_hh     = (const float*)d_in[19];
  const float* b_lstm   = (const float*)d_in[20];
  const float* g_W      = (const float*)d_in[21];
  const float* g_We     = (const float*)d_in[22];
  const float* g_asrc   = (const float*)d_in[23];
  const float* g_adst   = (const float*)d_in[24];
  const float* g_aedge  = (const float*)d_in[25];
  const float* g_lng    = (const float*)d_in[26];
  const float* g_lnb    = (const float*)d_in[27];
  const float* hn_w1    = (const float*)d_in[28];
  const float* hn_b1    = (const float*)d_in[29];
  const float* hn_w2    = (const float*)d_in[30];
  const float* hn_b2    = (const float*)d_in[31];
  const float* he_w1    = (const float*)d_in[32];
  const float* he_b1    = (const float*)d_in[33];
  const float* he_w2    = (const float*)d_in[34];
  const float* he_b2    = (const float*)d_in[35];

  const int* src = eidx;
  const int* dst = eidx + E_;
  float* outp = (float*)d_out;
  float* ws = (float*)d_ws;

  // workspace layout (floats). total = 98,304,000 floats = 393,216,000 bytes
  const size_t A0 = 24576000;                 // after fused_seq
  float* fseq = ws;                           // 24,576,000 (B*T*N*256)
  float* tok  = ws + A0;                      // 18,432,000 (stage A chunk)
  float* qkv  = ws + A0 + 18432000;           // 55,296,000 (stage A chunk)
  float* ow   = tok;                          // reuse tok for o@wo output
  // stage B aliases (stage A scratch is dead by then):
  float* eemb   = ws + A0;                    // 12,288,000
  float* ewtg   = ws + A0 + 12288000;         // 12,288,000
  float* elogtg = ws + A0 + 24576000;         //    384,000
  float* h      = ws + A0 + 24960000;         //  3,072,000
  float* c      = ws + A0 + 28032000;         //  3,072,000
  float* xw     = ws + A0 + 31104000;         //  3,072,000
  float* sal    = ws + A0 + 34176000;         //     96,000
  float* dal    = ws + A0 + 34272000;         //     96,000
  float* logbuf = ws + A0 + 34368000;         //    384,000
  unsigned* mmax = (unsigned*)(ws + A0 + 34752000); // 96,000
  float* ssum   = ws + A0 + 34848000;         //     96,000
  float* gat    = ws + A0 + 34944000;         //  3,072,000
  float* gates  = ws + A0 + 38016000;         // 12,288,000
  float* ewl    = ws + A0 + 50304000;         // 12,288,000
  float* elogl  = ws + A0 + 62592000;         //    384,000
  float* hg     = ws + A0 + 62976000;         //      1,024
  // end-phase aliases:
  float* ef     = ws + A0;                    // 24,576,000 (over eemb/ewtg)
  float* hide   = ws + A0 + 38016000;         //  6,144,000 (over gates)
  float* hidn   = ws + A0 + 50304000;         //  5,376,000 (over ewl)

  auto gemm = [&](const float* A, const float* W, const float* bias, float* C,
                  int M, int N, int K, int lda, int flags,
                  int mDiv = 0, int mOuter = 0, int mOff = 0) {
    dim3 grid((N + 63) / 64, (M + 63) / 64);
    gemm_k<<<grid, dim3(256), 0, stream>>>(A, W, bias, C, M, N, K, lda, flags,
                                           mDiv, mOuter, mOff);
  };

  // ---------------- Stage A: token attention + fused layernorm -------------
  for (int b = 0; b < B_; ++b) {
    gather_tok_k<<<18000, 256, 0, stream>>>(env, infra, robot, tok, b);
    // qkv = tok @ wqkv + bqkv   (72000 x 768)
    gemm(tok, wqkv, bqkv, qkv, 72000, 768, 256, 256, 0);
    // 3x3 attention per (node,head); writes O into q slots of qkv
    attn_k<<<750, 256, 0, stream>>>(qkv, 24000);
    // ow = O @ wo + bo          (72000 x 256), A strided inside qkv
    gemm(qkv, wo, bo, ow, 72000, 256, 256, 768, 0);
    // mean over 3 tokens + LN -> fused_seq[b]
    meanln_k<<<24000, 64, 0, stream>>>(ow, lnf_g, lnf_b,
                                       fseq + (size_t)b * 24000 * 256);
  }

  // ---------------- Stage B: GAT-LSTM ----------------
  hipMemsetAsync(h, 0, 12288000, stream);
  hipMemsetAsync(c, 0, 12288000, stream);

  // edge_emb = relu(edge_attr @ we_emb + be_emb)   (48000 x 256, K=8)
  gemm(edgeattr, we_emb, be_emb, eemb, 48000, 256, 8, 8, 2);
  // ew_tg = edge_emb @ tg_We
  gemm(eemb, tg_We, nullptr, ewtg, 48000, 256, 256, 256, 0);
  elog_k<<<1500, 256, 0, stream>>>(ewtg, tg_aedge, elogtg, 48000);

  for (int t = 0; t < T_; ++t) {
    // xw = x_t @ tg_W ; x_t rows remapped out of fused_seq
    gemm(fseq, tg_W, nullptr, xw, 12000, 256, 256, 256, 0, N_, T_ * N_, t * N_);
    alphas_k<<<375, 256, 0, stream>>>(xw, tg_asrc, tg_adst, sal, dal, 12000);
    hipMemsetAsync(mmax, 0, 384000, stream);
    hipMemsetAsync(ssum, 0, 384000, stream);
    hipMemsetAsync(gat, 0, 12288000, stream);
    logitmax_k<<<1500, 256, 0, stream>>>(sal, dal, elogtg, src, dst, logbuf, mmax);
    expsum_k<<<1500, 256, 0, stream>>>(logbuf, mmax, dst, ssum);
    scatter_k<<<1500, 256, 0, stream>>>(logbuf, ssum, xw, ewtg, src, dst, gat);
    // gates = gat @ w_ih + b_lstm ; gates += h @ w_hh
    gemm(gat, w_ih, b_lstm, gates, 12000, 1024, 256, 256, 0);
    gemm(h, w_hh, nullptr, gates, 12000, 1024, 256, 256, 1);
    lstm_k<<<12000, 256, 0, stream>>>(gates, h, c);
  }

  // ---------------- 3 GAT layers with residual LN ----------------
  for (int l = 0; l < 3; ++l) {
    gemm(eemb, g_We + (size_t)l * 65536, nullptr, ewl, 48000, 256, 256, 256, 0);
    elog_k<<<1500, 256, 0, stream>>>(ewl, g_aedge + l * 256, elogl, 48000);
    gemm(h, g_W + (size_t)l * 65536, nullptr, xw, 12000, 256, 256, 256, 0);
    alphas_k<<<375, 256, 0, stream>>>(xw, g_asrc + l * 256, g_adst + l * 256, sal, dal, 12000);
    hipMemsetAsync(mmax, 0, 384000, stream);
    hipMemsetAsync(ssum, 0, 384000, stream);
    hipMemsetAsync(gat, 0, 12288000, stream);
    logitmax_k<<<1500, 256, 0, stream>>>(sal, dal, elogl, src, dst, logbuf, mmax);
    expsum_k<<<1500, 256, 0, stream>>>(logbuf, mmax, dst, ssum);
    scatter_k<<<1500, 256, 0, stream>>>(logbuf, ssum, xw, ewl, src, dst, gat);
    resln_k<<<12000, 64, 0, stream>>>(h, gat, g_lng + l * 256, g_lnb + l * 256);
  }

  // ---------------- Heads ----------------
  for (int j = 0; j < 7; ++j)
    gemm(h, hn_w1 + (size_t)j * 16384, hn_b1 + j * 64,
         hidn + (size_t)j * 768000, 12000, 64, 256, 256, 2);
  nh2_k<<<(84000 + 255) / 256, 256, 0, stream>>>(hidn, hn_w2, hn_b2, outp);

  hglob_k<<<4, 256, 0, stream>>>(h, hg);
  freq_k<<<4, 64, 0, stream>>>(hg, hn_w1 + 7 * 16384, hn_b1 + 7 * 64,
                               hn_w2 + 7 * 64, hn_b2 + 7, outp);

  ef_k<<<24000, 256, 0, stream>>>(h, src, dst, ef);
  for (int jj = 0; jj < 2; ++jj)
    gemm(ef, he_w1 + (size_t)jj * 32768, he_b1 + jj * 64,
         hide + (size_t)jj * 3072000, 48000, 64, 512, 512, 2);
  eh2_k<<<(96000 + 255) / 256, 256, 0, stream>>>(hide, he_w2, he_b2, outp);
}

// Round 2
// 10526.653 us; speedup vs baseline: 1.2693x; 1.2693x over previous
//
#include <hip/hip_runtime.h>
#include <hip/hip_bf16.h>
#include <math.h>

#define DEV __device__ __forceinline__

namespace {
constexpr int B_ = 4, T_ = 8, N_ = 3000, E_ = 12000;
constexpr int OUTS_ = 45001;  // per-batch output stride: N*7 + E + E + 1
}

using bf16x8 = __attribute__((ext_vector_type(8))) short;
using f32x4  = __attribute__((ext_vector_type(4))) float;

DEV float sigm_(float x) { return 1.0f / (1.0f + expf(-x)); }
DEV float softplus_(float x) { return fmaxf(x, 0.0f) + log1pf(expf(-fabsf(x))); }
DEV unsigned fenc_(float f) {
  unsigned u = __float_as_uint(f);
  return (u & 0x80000000u) ? ~u : (u | 0x80000000u);
}
DEV float fdec_(unsigned u) {
  return (u & 0x80000000u) ? __uint_as_float(u ^ 0x80000000u) : __uint_as_float(~u);
}
DEV float wred_(float v) {
  #pragma unroll
  for (int o = 32; o > 0; o >>= 1) v += __shfl_xor(v, o, 64);
  return v;
}
DEV unsigned short f2bf(float x) {  // RNE fp32->bf16
  unsigned u = __float_as_uint(x);
  return (unsigned short)((u + 0x7FFFu + ((u >> 16) & 1u)) >> 16);
}
DEV unsigned f2bf2(float a, float b) {
  return (unsigned)f2bf(a) | ((unsigned)f2bf(b) << 16);
}

// ---------------------------------------------------------------------------
// Weight transpose+convert: Wt[n*K+k] = bf16(W[k*N+n])
// ---------------------------------------------------------------------------
__global__ void wt_k(const float* __restrict__ W, unsigned short* __restrict__ Wt,
                     int K, int N)
{
  const int idx = blockIdx.x * blockDim.x + threadIdx.x;
  if (idx >= K * N) return;
  const int k = idx / N, n = idx - k * N;
  Wt[(size_t)n * K + k] = f2bf(W[idx]);
}

// ---------------------------------------------------------------------------
// MFMA bf16 GEMM: C[M,N] = A[M,K](fp32) @ W[K,N] via Wt(bf16,[N][K])
// (+bias) (+C if flags&1) (relu if flags&2). K%32==0, N%64==0.
// Optional A logical-row remap: phys = (r/mDiv)*mOuter + mOff + r%mDiv
// Tile: 128x64, 4 waves each 64x32 (4x2 frags of 16x16), BK=32.
// ---------------------------------------------------------------------------
__global__ __launch_bounds__(256) void gemm_mfma_k(
    const float* __restrict__ A, const unsigned short* __restrict__ Wt,
    const float* __restrict__ bias, float* __restrict__ C,
    int M, int N, int K, int lda, int flags,
    int mDiv, int mOuter, int mOff)
{
  __shared__ unsigned short Al[128 * 40];  // [row][k], pad to 40 elems
  __shared__ unsigned short Bl[64 * 40];   // [col][k], pad to 40 elems
  const int tid = threadIdx.x;
  const int bm = blockIdx.y * 128;
  const int bn = blockIdx.x * 64;
  const int lane = tid & 63;
  const int wv = tid >> 6;
  const int wm = (wv >> 1) * 64;
  const int wn = (wv & 1) * 32;
  // A staging: thread -> (row 0..127, colseg 0/16)
  const int s_row = tid >> 1;
  const int s_cb = (tid & 1) * 16;
  const int grow = bm + s_row;
  const float* Arow = nullptr;
  if (grow < M) {
    int r = grow;
    if (mDiv > 0) r = (r / mDiv) * mOuter + mOff + (r % mDiv);
    Arow = A + (size_t)r * lda;
  }
  // B staging: thread -> (col 0..63, kseg 0/8/16/24)
  const int b_col = tid >> 2;
  const int b_ks = (tid & 3) * 8;
  const unsigned short* Wrow = Wt + (size_t)(bn + b_col) * K + b_ks;

  f32x4 acc[4][2] = {};
  const int l15 = lane & 15;
  const int lk = (lane >> 4) * 8;

  for (int k0 = 0; k0 < K; k0 += 32) {
    unsigned abuf[8];
    if (Arow) {
      const float* p = Arow + k0 + s_cb;
      #pragma unroll
      for (int i = 0; i < 4; ++i) {
        const float4 v = *(const float4*)(p + i * 4);
        abuf[i * 2 + 0] = f2bf2(v.x, v.y);
        abuf[i * 2 + 1] = f2bf2(v.z, v.w);
      }
    } else {
      #pragma unroll
      for (int i = 0; i < 8; ++i) abuf[i] = 0;
    }
    *(uint4*)&Al[s_row * 40 + s_cb] = *(uint4*)&abuf[0];
    *(uint4*)&Al[s_row * 40 + s_cb + 8] = *(uint4*)&abuf[4];
    *(bf16x8*)&Bl[b_col * 40 + b_ks] = *(const bf16x8*)(Wrow + k0);
    __syncthreads();
    bf16x8 af[4], bfr[2];
    #pragma unroll
    for (int m = 0; m < 4; ++m)
      af[m] = *(const bf16x8*)&Al[(wm + m * 16 + l15) * 40 + lk];
    #pragma unroll
    for (int n = 0; n < 2; ++n)
      bfr[n] = *(const bf16x8*)&Bl[(wn + n * 16 + l15) * 40 + lk];
    #pragma unroll
    for (int m = 0; m < 4; ++m)
      #pragma unroll
      for (int n = 0; n < 2; ++n)
        acc[m][n] = __builtin_amdgcn_mfma_f32_16x16x32_bf16(af[m], bfr[n], acc[m][n], 0, 0, 0);
    __syncthreads();
  }
  const int r4 = (lane >> 4) * 4;
  #pragma unroll
  for (int m = 0; m < 4; ++m) {
    #pragma unroll
    for (int n = 0; n < 2; ++n) {
      const int col = bn + wn + n * 16 + l15;
      const float bv = bias ? bias[col] : 0.f;
      #pragma unroll
      for (int r = 0; r < 4; ++r) {
        const int row = bm + wm + m * 16 + r4 + r;
        if (row >= M) continue;
        float v = acc[m][n][r] + bv;
        float* cp = C + (size_t)row * N + col;
        if (flags & 1) v += *cp;
        if (flags & 2) v = fmaxf(v, 0.f);
        *cp = v;
      }
    }
  }
}

// ---------------------------------------------------------------------------
// fp32 fallback GEMM (used only for K=8 edge-emb GEMM)
// ---------------------------------------------------------------------------
__global__ __launch_bounds__(256) void gemm_k(
    const float* __restrict__ A, const float* __restrict__ W,
    const float* __restrict__ bias, float* __restrict__ C,
    int M, int N, int K, int lda, int flags)
{
  __shared__ float As[16][68];
  __shared__ float Ws[16][64];
  const int tid = threadIdx.x;
  const int bm = blockIdx.y * 64;
  const int bn = blockIdx.x * 64;
  const int tx = tid & 15;
  const int ty = tid >> 4;
  const int ar = tid >> 2;
  const int ac = (tid & 3) << 2;
  const int wr = tid >> 4;
  const int wc = (tid & 15) << 2;
  const int grow = bm + ar;
  const float* Arow = (grow < M) ? A + (size_t)grow * lda : nullptr;
  float acc[4][4] = {};
  for (int k0 = 0; k0 < K; k0 += 16) {
    float4 av = make_float4(0.f, 0.f, 0.f, 0.f);
    if (Arow) {
      av.x = (k0 + ac + 0 < K) ? Arow[k0 + ac + 0] : 0.f;
      av.y = (k0 + ac + 1 < K) ? Arow[k0 + ac + 1] : 0.f;
      av.z = (k0 + ac + 2 < K) ? Arow[k0 + ac + 2] : 0.f;
      av.w = (k0 + ac + 3 < K) ? Arow[k0 + ac + 3] : 0.f;
    }
    As[ac + 0][ar] = av.x;
    As[ac + 1][ar] = av.y;
    As[ac + 2][ar] = av.z;
    As[ac + 3][ar] = av.w;
    float4 wv = make_float4(0.f, 0.f, 0.f, 0.f);
    if (k0 + wr < K) {
      const int gc = bn + wc;
      const float* wp = W + (size_t)(k0 + wr) * N + gc;
      wv.x = (gc + 0 < N) ? wp[0] : 0.f;
      wv.y = (gc + 1 < N) ? wp[1] : 0.f;
      wv.z = (gc + 2 < N) ? wp[2] : 0.f;
      wv.w = (gc + 3 < N) ? wp[3] : 0.f;
    }
    *(float4*)&Ws[wr][wc] = wv;
    __syncthreads();
    #pragma unroll
    for (int kk = 0; kk < 16; ++kk) {
      const float4 a = *(const float4*)&As[kk][ty << 2];
      const float4 b = *(const float4*)&Ws[kk][tx << 2];
      acc[0][0] += a.x * b.x; acc[0][1] += a.x * b.y; acc[0][2] += a.x * b.z; acc[0][3] += a.x * b.w;
      acc[1][0] += a.y * b.x; acc[1][1] += a.y * b.y; acc[1][2] += a.y * b.z; acc[1][3] += a.y * b.w;
      acc[2][0] += a.z * b.x; acc[2][1] += a.z * b.y; acc[2][2] += a.z * b.z; acc[2][3] += a.z * b.w;
      acc[3][0] += a.w * b.x; acc[3][1] += a.w * b.y; acc[3][2] += a.w * b.z; acc[3][3] += a.w * b.w;
    }
    __syncthreads();
  }
  #pragma unroll
  for (int i = 0; i < 4; ++i) {
    const int row = bm + (ty << 2) + i;
    if (row >= M) continue;
    float* crow = C + (size_t)row * N;
    #pragma unroll
    for (int j = 0; j < 4; ++j) {
      const int col = bn + (tx << 2) + j;
      if (col >= N) continue;
      float v = acc[i][j];
      if (bias) v += bias[col];
      if (flags & 1) v += crow[col];
      if (flags & 2) v = fmaxf(v, 0.f);
      crow[col] = v;
    }
  }
}

// ---------------------------------------------------------------------------
// Stage A kernels
// ---------------------------------------------------------------------------
// Gather tokens for chunk at node-row base (=(b*T+t0)*N), 12000 nodes
__global__ void gather_tok_k(const float* __restrict__ env,
                             const float* __restrict__ infra,
                             const float* __restrict__ robot,
                             float* __restrict__ tok, int base)
{
  const int idx = blockIdx.x * blockDim.x + threadIdx.x;  // float4 units
  const int total4 = 12000 * 3 * 64;
  if (idx >= total4) return;
  const int flat = idx << 2;
  const int d = flat & 255;
  const int rs = flat >> 8;
  const int s = rs % 3;
  const int tn = rs / 3;
  const float* srcp = (s == 0 ? env : (s == 1 ? infra : robot));
  const float4 v = *(const float4*)(srcp + ((size_t)(base + tn)) * 256 + d);
  *(float4*)(tok + (size_t)flat) = v;
}

// per-(node,head) 3x3 attention; writes O in-place into the Q slots of qkv
__global__ void attn_k(float* __restrict__ qkv, int nodes)
{
  const int idx = blockIdx.x * blockDim.x + threadIdx.x;
  if (idx >= nodes * 8) return;
  const int node = idx >> 3, h = idx & 7;
  float* base = qkv + (size_t)node * 2304 + h * 32;
  float att[3][3];
  #pragma unroll
  for (int s = 0; s < 3; ++s) {
    const float* q = base + s * 768;
    #pragma unroll
    for (int t = 0; t < 3; ++t) {
      const float* k = base + t * 768 + 256;
      float d = 0.f;
      #pragma unroll
      for (int i = 0; i < 32; i += 4) {
        const float4 qv = *(const float4*)(q + i);
        const float4 kv = *(const float4*)(k + i);
        d += qv.x * kv.x + qv.y * kv.y + qv.z * kv.z + qv.w * kv.w;
      }
      att[s][t] = d * 0.17677669529663687f;
    }
  }
  #pragma unroll
  for (int s = 0; s < 3; ++s) {
    const float m = fmaxf(att[s][0], fmaxf(att[s][1], att[s][2]));
    const float e0 = expf(att[s][0] - m);
    const float e1 = expf(att[s][1] - m);
    const float e2 = expf(att[s][2] - m);
    const float inv = 1.f / (e0 + e1 + e2);
    att[s][0] = e0 * inv; att[s][1] = e1 * inv; att[s][2] = e2 * inv;
  }
  #pragma unroll
  for (int s = 0; s < 3; ++s) {
    float o[32];
    #pragma unroll
    for (int i = 0; i < 32; ++i) o[i] = 0.f;
    #pragma unroll
    for (int t = 0; t < 3; ++t) {
      const float* v = base + t * 768 + 512;
      const float w = att[s][t];
      #pragma unroll
      for (int i = 0; i < 32; ++i) o[i] += w * v[i];
    }
    float* op = base + s * 768;
    #pragma unroll
    for (int i = 0; i < 32; i += 4)
      *(float4*)(op + i) = make_float4(o[i], o[i + 1], o[i + 2], o[i + 3]);
  }
}

// mean over the 3 token rows + LayerNorm -> fused_seq row. 1 wave per node.
__global__ __launch_bounds__(64) void meanln_k(
    const float* __restrict__ OW, const float* __restrict__ g,
    const float* __restrict__ bta, float* __restrict__ outp)
{
  const int row = blockIdx.x;
  const int d0 = threadIdx.x << 2;
  const float* r0 = OW + (size_t)row * 768;
  const float4 a = *(const float4*)(r0 + d0);
  const float4 b4 = *(const float4*)(r0 + 256 + d0);
  const float4 c4 = *(const float4*)(r0 + 512 + d0);
  float x[4];
  x[0] = (a.x + b4.x + c4.x) * (1.f / 3.f);
  x[1] = (a.y + b4.y + c4.y) * (1.f / 3.f);
  x[2] = (a.z + b4.z + c4.z) * (1.f / 3.f);
  x[3] = (a.w + b4.w + c4.w) * (1.f / 3.f);
  float s = x[0] + x[1] + x[2] + x[3];
  s = wred_(s);
  const float mean = s * (1.f / 256.f);
  float vs = 0.f;
  #pragma unroll
  for (int i = 0; i < 4; ++i) { const float dd = x[i] - mean; vs += dd * dd; }
  vs = wred_(vs);
  const float inv = 1.0f / sqrtf(vs * (1.f / 256.f) + 1e-5f);
  const float4 gv = *(const float4*)(g + d0);
  const float4 bv = *(const float4*)(bta + d0);
  float4 o;
  o.x = (x[0] - mean) * inv * gv.x + bv.x;
  o.y = (x[1] - mean) * inv * gv.y + bv.y;
  o.z = (x[2] - mean) * inv * gv.z + bv.z;
  o.w = (x[3] - mean) * inv * gv.w + bv.w;
  *(float4*)(outp + (size_t)row * 256 + d0) = o;
}

// ---------------------------------------------------------------------------
// GAT kernels
// ---------------------------------------------------------------------------
__global__ void alphas_k(const float* __restrict__ xw, const float* __restrict__ as,
                         const float* __restrict__ ad, float* __restrict__ sal,
                         float* __restrict__ dal, int rows)
{
  const int idx = blockIdx.x * blockDim.x + threadIdx.x;
  if (idx >= rows * 8) return;
  const int row = idx >> 3, h = idx & 7;
  const float* x = xw + (size_t)row * 256 + h * 32;
  const float* a1 = as + h * 32;
  const float* a2 = ad + h * 32;
  float s = 0.f, d = 0.f;
  #pragma unroll
  for (int i = 0; i < 32; ++i) { s += x[i] * a1[i]; d += x[i] * a2[i]; }
  sal[idx] = s; dal[idx] = d;
}

__global__ void elog_k(const float* __restrict__ ew, const float* __restrict__ ae,
                       float* __restrict__ el, int rows)
{
  const int idx = blockIdx.x * blockDim.x + threadIdx.x;
  if (idx >= rows * 8) return;
  const int row = idx >> 3, h = idx & 7;
  const float* x = ew + (size_t)row * 256 + h * 32;
  const float* a1 = ae + h * 32;
  float s = 0.f;
  #pragma unroll
  for (int i = 0; i < 32; ++i) s += x[i] * a1[i];
  el[idx] = s;
}

__global__ void logitmax_k(const float* __restrict__ sal, const float* __restrict__ dal,
                           const float* __restrict__ el, const int* __restrict__ src,
                           const int* __restrict__ dst, float* __restrict__ logbuf,
                           unsigned* __restrict__ mmax)
{
  const int idx = blockIdx.x * blockDim.x + threadIdx.x;
  if (idx >= B_ * E_ * 8) return;
  const int b = idx / (E_ * 8);
  const int r = idx - b * E_ * 8;
  const int e = r >> 3, h = r & 7;
  const int s = src[e], d = dst[e];
  float lg = sal[(b * N_ + s) * 8 + h] + dal[(b * N_ + d) * 8 + h] + el[idx];
  lg = lg > 0.f ? lg : 0.2f * lg;
  logbuf[idx] = lg;
  atomicMax(&mmax[(b * N_ + d) * 8 + h], fenc_(lg));
}

__global__ void expsum_k(float* __restrict__ logbuf, const unsigned* __restrict__ mmax,
                         const int* __restrict__ dst, float* __restrict__ ssum)
{
  const int idx = blockIdx.x * blockDim.x + threadIdx.x;
  if (idx >= B_ * E_ * 8) return;
  const int b = idx / (E_ * 8);
  const int r = idx - b * E_ * 8;
  const int e = r >> 3, h = r & 7;
  const int d = dst[e];
  const float m = fdec_(mmax[(b * N_ + d) * 8 + h]);
  const float ex = expf(logbuf[idx] - m);
  logbuf[idx] = ex;
  atomicAdd(&ssum[(b * N_ + d) * 8 + h], ex);
}

__global__ void scatter_k(const float* __restrict__ logbuf, const float* __restrict__ ssum,
                          const float* __restrict__ xw, const float* __restrict__ ew,
                          const int* __restrict__ src, const int* __restrict__ dst,
                          float* __restrict__ outp)
{
  const int idx = blockIdx.x * blockDim.x + threadIdx.x;
  if (idx >= B_ * E_ * 8) return;
  const int b = idx / (E_ * 8);
  const int r = idx - b * E_ * 8;
  const int e = r >> 3, h = r & 7;
  const int s = src[e], d = dst[e];
  const float w = logbuf[idx] / (ssum[(b * N_ + d) * 8 + h] + 1e-16f);
  const float* xs = xw + ((size_t)(b * N_ + s)) * 256 + h * 32;
  const float* ee = ew + ((size_t)(b * E_ + e)) * 256 + h * 32;
  float* op = outp + ((size_t)(b * N_ + d)) * 256 + h * 32;
  #pragma unroll
  for (int i = 0; i < 32; ++i) atomicAdd(op + i, (xs[i] + ee[i]) * w);
}

__global__ __launch_bounds__(256) void lstm_k(const float* __restrict__ gates,
                                              float* __restrict__ h, float* __restrict__ c)
{
  const int row = blockIdx.x;
  const int d = threadIdx.x;
  const float* g = gates + (size_t)row * 1024;
  const float i_ = sigm_(g[d]);
  const float f_ = sigm_(g[256 + d]);
  const float gg = tanhf(g[512 + d]);
  const float o_ = sigm_(g[768 + d]);
  const size_t idx = (size_t)row * 256 + d;
  const float cn = f_ * c[idx] + i_ * gg;
  c[idx] = cn;
  h[idx] = o_ * tanhf(cn);
}

__global__ __launch_bounds__(64) void resln_k(float* __restrict__ h,
                                              const float* __restrict__ add,
                                              const float* __restrict__ g,
                                              const float* __restrict__ bta)
{
  const int row = blockIdx.x;
  const int d0 = threadIdx.x << 2;
  float* hp = h + (size_t)row * 256;
  const float4 hv = *(const float4*)(hp + d0);
  const float4 av = *(const float4*)(add + (size_t)row * 256 + d0);
  float x[4] = { hv.x + av.x, hv.y + av.y, hv.z + av.z, hv.w + av.w };
  float s = x[0] + x[1] + x[2] + x[3];
  s = wred_(s);
  const float mean = s * (1.f / 256.f);
  float vs = 0.f;
  #pragma unroll
  for (int i = 0; i < 4; ++i) { const float dd = x[i] - mean; vs += dd * dd; }
  vs = wred_(vs);
  const float inv = 1.0f / sqrtf(vs * (1.f / 256.f) + 1e-5f);
  const float4 gv = *(const float4*)(g + d0);
  const float4 bv = *(const float4*)(bta + d0);
  float4 o;
  o.x = (x[0] - mean) * inv * gv.x + bv.x;
  o.y = (x[1] - mean) * inv * gv.y + bv.y;
  o.z = (x[2] - mean) * inv * gv.z + bv.z;
  o.w = (x[3] - mean) * inv * gv.w + bv.w;
  *(float4*)(hp + d0) = o;
}

// ---------------------------------------------------------------------------
// Head kernels
// ---------------------------------------------------------------------------
// hidden is [B*N][448] (7 heads x 64 packed)
__global__ void nh2_k(const float* __restrict__ hidden, const float* __restrict__ w2,
                      const float* __restrict__ b2, float* __restrict__ outp)
{
  const int idx = blockIdx.x * blockDim.x + threadIdx.x;
  if (idx >= B_ * N_ * 7) return;
  const int row = idx / 7, j = idx % 7;
  const float* hp = hidden + (size_t)row * 448 + j * 64;
  const float* wp = w2 + j * 64;
  float a = 0.f;
  #pragma unroll
  for (int u = 0; u < 64; ++u) a += hp[u] * wp[u];
  a += b2[j];
  if (j == 0 || j == 6) a = sigm_(a);
  else if (j == 1) a = softplus_(a);
  const int b = row / N_, n = row % N_;
  outp[(size_t)b * OUTS_ + n * 7 + j] = a;
}

__global__ __launch_bounds__(256) void hglob_k(const float* __restrict__ h, float* __restrict__ hg)
{
  const int b = blockIdx.x;
  const int d = threadIdx.x;
  float s = 0.f;
  for (int n = 0; n < N_; ++n) s += h[((size_t)(b * N_ + n)) * 256 + d];
  hg[b * 256 + d] = s * (1.f / (float)N_);
}

__global__ __launch_bounds__(64) void freq_k(const float* __restrict__ hg,
                                             const float* __restrict__ w1, const float* __restrict__ b1,
                                             const float* __restrict__ w2, const float* __restrict__ b2,
                                             float* __restrict__ outp)
{
  const int b = blockIdx.x;
  const int u = threadIdx.x;
  float a = b1[u];
  for (int k = 0; k < 256; ++k) a += hg[b * 256 + k] * w1[k * 64 + u];
  a = fmaxf(a, 0.f) * w2[u];
  a = wred_(a);
  if (u == 0) outp[(size_t)b * OUTS_ + 45000] = a + b2[0];
}

__global__ void ef_k(const float* __restrict__ h, const int* __restrict__ src,
                     const int* __restrict__ dst, float* __restrict__ ef)
{
  const int idx = blockIdx.x * blockDim.x + threadIdx.x;  // float4 units
  if (idx >= B_ * E_ * 128) return;
  const int q = idx & 127;
  const int row = idx >> 7;
  const int b = row / E_, e = row % E_;
  const int d = q << 2;
  const float* p = (d < 256)
      ? h + ((size_t)(b * N_ + src[e])) * 256 + d
      : h + ((size_t)(b * N_ + dst[e])) * 256 + (d - 256);
  *(float4*)(ef + (size_t)row * 512 + d) = *(const float4*)p;
}

// hidden is [B*E][128] (2 heads x 64 packed)
__global__ void eh2_k(const float* __restrict__ hidden, const float* __restrict__ w2,
                      const float* __restrict__ b2, float* __restrict__ outp)
{
  const int idx = blockIdx.x * blockDim.x + threadIdx.x;
  if (idx >= 2 * B_ * E_) return;
  const int jj = idx / (B_ * E_);
  const int r = idx - jj * (B_ * E_);
  const int b = r / E_, e = r % E_;
  const float* hp = hidden + (size_t)r * 128 + jj * 64;
  const float* wp = w2 + jj * 64;
  float a = 0.f;
  #pragma unroll
  for (int u = 0; u < 64; ++u) a += hp[u] * wp[u];
  a += b2[jj];
  outp[(size_t)b * OUTS_ + 21000 + jj * 12000 + e] = a;
}

// ---------------------------------------------------------------------------
extern "C" void kernel_launch(void* const* d_in, const int* in_sizes, int n_in,
                              void* d_out, int out_size, void* d_ws, size_t ws_size,
                              hipStream_t stream)
{
  const float* env      = (const float*)d_in[0];
  const float* infra    = (const float*)d_in[1];
  const float* robot    = (const float*)d_in[2];
  const float* edgeattr = (const float*)d_in[3];
  const int*   eidx     = (const int*)d_in[4];
  const float* wqkv     = (const float*)d_in[5];
  const float* bqkv     = (const float*)d_in[6];
  const float* wo       = (const float*)d_in[7];
  const float* bo       = (const float*)d_in[8];
  const float* lnf_g    = (const float*)d_in[9];
  const float* lnf_b    = (const float*)d_in[10];
  const float* we_emb   = (const float*)d_in[11];
  const float* be_emb   = (const float*)d_in[12];
  const float* tg_W     = (const float*)d_in[13];
  const float* tg_We    = (const float*)d_in[14];
  const float* tg_asrc  = (const float*)d_in[15];
  const float* tg_adst  = (const float*)d_in[16];
  const float* tg_aedge = (const float*)d_in[17];
  const float* w_ih     = (const float*)d_in[18];
  const float* w_hh     = (const float*)d_in[19];
  const float* b_lstm   = (const float*)d_in[20];
  const float* g_W      = (const float*)d_in[21];
  const float* g_We     = (const float*)d_in[22];
  const float* g_asrc   = (const float*)d_in[23];
  const float* g_adst   = (const float*)d_in[24];
  const float* g_aedge  = (const float*)d_in[25];
  const float* g_lng    = (const float*)d_in[26];
  const float* g_lnb    = (const float*)d_in[27];
  const float* hn_w1    = (const float*)d_in[28];
  const float* hn_b1    = (const float*)d_in[29];
  const float* hn_w2    = (const float*)d_in[30];
  const float* hn_b2    = (const float*)d_in[31];
  const float* he_w1    = (const float*)d_in[32];
  const float* he_b1    = (const float*)d_in[33];
  const float* he_w2    = (const float*)d_in[34];
  const float* he_b2    = (const float*)d_in[35];

  const int* src = eidx;
  const int* dst = eidx + E_;
  float* outp = (float*)d_out;
  float* ws = (float*)d_ws;

  // ---- workspace layout (floats) ----
  const size_t A0 = 24576000;                 // fseq size (B*T*N*256)
  float* fseq = ws;
  float* tok  = ws + A0;                      //  9,216,000 (stage A half-chunk)
  float* qkv  = ws + A0 + 9216000;            // 27,648,000
  float* ow   = tok;
  // stage B aliases:
  float* eemb   = ws + A0;                    // 12,288,000
  float* ewtg   = ws + A0 + 12288000;         // 12,288,000
  float* elogtg = ws + A0 + 24576000;         //    384,000
  float* h      = ws + A0 + 24960000;         //  3,072,000
  float* c      = ws + A0 + 28032000;         //  3,072,000
  float* xw     = ws + A0 + 31104000;         //  3,072,000
  float* sal    = ws + A0 + 34176000;         //     96,000
  float* dal    = ws + A0 + 34272000;         //     96,000
  float* logbuf = ws + A0 + 34368000;         //    384,000
  unsigned* mmax = (unsigned*)(ws + A0 + 34752000); // 96,000
  float* ssum   = ws + A0 + 34848000;         //     96,000
  float* gat    = ws + A0 + 34944000;         //  3,072,000
  float* gates  = ws + A0 + 38016000;         // 12,288,000
  float* ewl    = ws + A0 + 50304000;         // 12,288,000
  float* elogl  = ws + A0 + 62592000;         //    384,000
  float* hg     = ws + A0 + 62976000;         //      1,024
  // end-phase aliases:
  float* ef     = ws + A0;                    // 24,576,000
  float* hide   = ws + A0 + 38016000;         //  6,144,000 ([B*E][128])
  float* hidn   = ws + A0 + 50304000;         //  5,376,000 ([B*N][448])
  // bf16 transposed weights (persistent; beyond stage-B usage)
  unsigned short* wtb = (unsigned short*)(ws + 87600000);
  unsigned short* wt_qkv = wtb;               // 196,608
  unsigned short* wt_wo  = wtb + 196608;      //  65,536
  unsigned short* wt_tgW = wtb + 262144;      //  65,536
  unsigned short* wt_tgWe= wtb + 327680;      //  65,536
  unsigned short* wt_wih = wtb + 393216;      // 262,144
  unsigned short* wt_whh = wtb + 655360;      // 262,144
  unsigned short* wt_gW  = wtb + 917504;      // 196,608 (3 layers)
  unsigned short* wt_gWe = wtb + 1114112;     // 196,608
  unsigned short* wt_hn  = wtb + 1310720;     // 114,688 (7 heads packed -> [448][256])
  unsigned short* wt_he  = wtb + 1425408;     //  65,536 (2 heads packed -> [128][512])

  auto mgemm = [&](const float* A, const unsigned short* Wt, const float* bias,
                   float* C, int M, int N, int K, int lda, int flags,
                   int mDiv = 0, int mOuter = 0, int mOff = 0) {
    dim3 grid(N / 64, (M + 127) / 128);
    gemm_mfma_k<<<grid, dim3(256), 0, stream>>>(A, Wt, bias, C, M, N, K, lda,
                                                flags, mDiv, mOuter, mOff);
  };
  auto cvt = [&](const float* W, unsigned short* Wt, int K, int N) {
    wt_k<<<(K * N + 255) / 256, 256, 0, stream>>>(W, Wt, K, N);
  };

  // ---- weight convert+transpose (bf16) ----
  cvt(wqkv, wt_qkv, 256, 768);
  cvt(wo, wt_wo, 256, 256);
  cvt(tg_W, wt_tgW, 256, 256);
  cvt(tg_We, wt_tgWe, 256, 256);
  cvt(w_ih, wt_wih, 256, 1024);
  cvt(w_hh, wt_whh, 256, 1024);
  for (int l = 0; l < 3; ++l) {
    cvt(g_W + (size_t)l * 65536, wt_gW + (size_t)l * 65536, 256, 256);
    cvt(g_We + (size_t)l * 65536, wt_gWe + (size_t)l * 65536, 256, 256);
  }
  for (int j = 0; j < 7; ++j)
    cvt(hn_w1 + (size_t)j * 16384, wt_hn + (size_t)j * 16384, 256, 64);
  for (int jj = 0; jj < 2; ++jj)
    cvt(he_w1 + (size_t)jj * 32768, wt_he + (size_t)jj * 32768, 512, 64);

  // ---------------- Stage A: token attention + fused layernorm -------------
  for (int b = 0; b < B_; ++b) {
    for (int half = 0; half < 2; ++half) {
      const int base = (b * T_ + half * 4) * N_;
      gather_tok_k<<<9000, 256, 0, stream>>>(env, infra, robot, tok, base);
      mgemm(tok, wt_qkv, bqkv, qkv, 36000, 768, 256, 256, 0);
      attn_k<<<375, 256, 0, stream>>>(qkv, 12000);
      mgemm(qkv, wt_wo, bo, ow, 36000, 256, 256, 768, 0);
      meanln_k<<<12000, 64, 0, stream>>>(ow, lnf_g, lnf_b, fseq + (size_t)base * 256);
    }
  }

  // ---------------- Stage B: GAT-LSTM ----------------
  hipMemsetAsync(h, 0, 12288000, stream);
  hipMemsetAsync(c, 0, 12288000, stream);

  {  // edge_emb = relu(edge_attr @ we_emb + be_emb)   (48000 x 256, K=8)
    dim3 grid(4, 750);
    gemm_k<<<grid, dim3(256), 0, stream>>>(edgeattr, we_emb, be_emb, eemb,
                                           48000, 256, 8, 8, 2);
  }
  mgemm(eemb, wt_tgWe, nullptr, ewtg, 48000, 256, 256, 256, 0);
  elog_k<<<1500, 256, 0, stream>>>(ewtg, tg_aedge, elogtg, 48000);

  for (int t = 0; t < T_; ++t) {
    mgemm(fseq, wt_tgW, nullptr, xw, 12000, 256, 256, 256, 0, N_, T_ * N_, t * N_);
    alphas_k<<<375, 256, 0, stream>>>(xw, tg_asrc, tg_adst, sal, dal, 12000);
    hipMemsetAsync(mmax, 0, 384000, stream);
    hipMemsetAsync(ssum, 0, 384000, stream);
    hipMemsetAsync(gat, 0, 12288000, stream);
    logitmax_k<<<1500, 256, 0, stream>>>(sal, dal, elogtg, src, dst, logbuf, mmax);
    expsum_k<<<1500, 256, 0, stream>>>(logbuf, mmax, dst, ssum);
    scatter_k<<<1500, 256, 0, stream>>>(logbuf, ssum, xw, ewtg, src, dst, gat);
    mgemm(gat, wt_wih, b_lstm, gates, 12000, 1024, 256, 256, 0);
    mgemm(h, wt_whh, nullptr, gates, 12000, 1024, 256, 256, 1);
    lstm_k<<<12000, 256, 0, stream>>>(gates, h, c);
  }

  // ---------------- 3 GAT layers with residual LN ----------------
  for (int l = 0; l < 3; ++l) {
    mgemm(eemb, wt_gWe + (size_t)l * 65536, nullptr, ewl, 48000, 256, 256, 256, 0);
    elog_k<<<1500, 256, 0, stream>>>(ewl, g_aedge + l * 256, elogl, 48000);
    mgemm(h, wt_gW + (size_t)l * 65536, nullptr, xw, 12000, 256, 256, 256, 0);
    alphas_k<<<375, 256, 0, stream>>>(xw, g_asrc + l * 256, g_adst + l * 256, sal, dal, 12000);
    hipMemsetAsync(mmax, 0, 384000, stream);
    hipMemsetAsync(ssum, 0, 384000, stream);
    hipMemsetAsync(gat, 0, 12288000, stream);
    logitmax_k<<<1500, 256, 0, stream>>>(sal, dal, elogl, src, dst, logbuf, mmax);
    expsum_k<<<1500, 256, 0, stream>>>(logbuf, mmax, dst, ssum);
    scatter_k<<<1500, 256, 0, stream>>>(logbuf, ssum, xw, ewl, src, dst, gat);
    resln_k<<<12000, 64, 0, stream>>>(h, gat, g_lng + l * 256, g_lnb + l * 256);
  }

  // ---------------- Heads ----------------
  // node heads: one packed GEMM [12000 x 448]
  mgemm(h, wt_hn, hn_b1, hidn, 12000, 448, 256, 256, 2);
  nh2_k<<<(84000 + 255) / 256, 256, 0, stream>>>(hidn, hn_w2, hn_b2, outp);

  hglob_k<<<4, 256, 0, stream>>>(h, hg);
  freq_k<<<4, 64, 0, stream>>>(hg, hn_w1 + 7 * 16384, hn_b1 + 7 * 64,
                               hn_w2 + 7 * 64, hn_b2 + 7, outp);

  ef_k<<<24000, 256, 0, stream>>>(h, src, dst, ef);
  // edge heads: one packed GEMM [48000 x 128], K=512
  mgemm(ef, wt_he, he_b1, hide, 48000, 128, 512, 512, 2);
  eh2_k<<<(96000 + 255) / 256, 256, 0, stream>>>(hide, he_w2, he_b2, outp);
}

// Round 3
// 2674.444 us; speedup vs baseline: 4.9959x; 3.9360x over previous
//
#include <hip/hip_runtime.h>
#include <hip/hip_bf16.h>
#include <math.h>

#define DEV __device__ __forceinline__

namespace {
constexpr int B_ = 4, T_ = 8, N_ = 3000, E_ = 12000;
constexpr int OUTS_ = 45001;  // per-batch output stride: N*7 + E + E + 1
}

using bf16x8 = __attribute__((ext_vector_type(8))) short;
using f32x4  = __attribute__((ext_vector_type(4))) float;

DEV float sigm_(float x) { return 1.0f / (1.0f + expf(-x)); }
DEV float softplus_(float x) { return fmaxf(x, 0.0f) + log1pf(expf(-fabsf(x))); }
DEV float wred_(float v) {
  #pragma unroll
  for (int o = 32; o > 0; o >>= 1) v += __shfl_xor(v, o, 64);
  return v;
}
DEV unsigned short f2bf(float x) {  // RNE fp32->bf16
  unsigned u = __float_as_uint(x);
  return (unsigned short)((u + 0x7FFFu + ((u >> 16) & 1u)) >> 16);
}
DEV unsigned f2bf2(float a, float b) {
  return (unsigned)f2bf(a) | ((unsigned)f2bf(b) << 16);
}

// ---------------------------------------------------------------------------
// Weight transpose+convert: Wt[n*dstStride + kOff + k] = bf16(W[k*N+n])
// ---------------------------------------------------------------------------
__global__ void wt_k(const float* __restrict__ W, unsigned short* __restrict__ Wt,
                     int K, int N, int dstStride, int kOff)
{
  const int idx = blockIdx.x * blockDim.x + threadIdx.x;
  if (idx >= K * N) return;
  const int k = idx / N, n = idx - k * N;
  Wt[(size_t)n * dstStride + kOff + k] = f2bf(W[idx]);
}

// ---------------------------------------------------------------------------
// CSR build (deterministic)
// ---------------------------------------------------------------------------
__global__ void hist_k(const int* __restrict__ dst, int* __restrict__ deg)
{
  const int e = blockIdx.x * blockDim.x + threadIdx.x;
  if (e < E_) atomicAdd(&deg[dst[e]], 1);
}

// single block, 256 threads: exclusive scan of deg[3000] -> roff[3001]
__global__ __launch_bounds__(256) void scan_k(const int* __restrict__ deg,
                                              int* __restrict__ roff)
{
  __shared__ int part[256];
  const int t = threadIdx.x;
  int loc[12];
  int s = 0;
  #pragma unroll
  for (int i = 0; i < 12; ++i) {
    const int n = t * 12 + i;
    loc[i] = s;
    s += (n < N_) ? deg[n] : 0;
  }
  part[t] = s;
  __syncthreads();
  if (t == 0) {
    int run = 0;
    for (int i = 0; i < 256; ++i) { const int v = part[i]; part[i] = run; run += v; }
  }
  __syncthreads();
  const int base = part[t];
  #pragma unroll
  for (int i = 0; i < 12; ++i) {
    const int n = t * 12 + i;
    if (n < N_) roff[n] = base + loc[i];
  }
  if (t == 0) roff[N_] = E_;
}

// stable fill: one wave per dst node scans all E edges with ballot
__global__ __launch_bounds__(256) void fill_k(const int* __restrict__ dst,
                                              const int* __restrict__ roff,
                                              int* __restrict__ eord)
{
  const int n = blockIdx.x * 4 + (threadIdx.x >> 6);
  if (n >= N_) return;
  const int lane = threadIdx.x & 63;
  const unsigned long long ltm = (1ull << lane) - 1ull;
  int cnt = roff[n];
  for (int c = 0; c < E_; c += 64) {
    const int e = c + lane;
    const bool m = (e < E_) && (dst[e] == n);
    const unsigned long long mask = __ballot(m);
    if (m) eord[cnt + __popcll(mask & ltm)] = e;
    cnt += __popcll(mask);
  }
}

// ---------------------------------------------------------------------------
// MFMA bf16 GEMM: C[M,N] = A[M,K](fp32) @ W[K,N] via Wt(bf16,[N][K])
// (+bias) (+C if flags&1) (relu if flags&2). K%32==0, N%64==0.
// Optional A logical-row remap: phys = (r/mDiv)*mOuter + mOff + r%mDiv
// Tile: 128x64, 4 waves each 64x32 (4x2 frags of 16x16), BK=32.
// ---------------------------------------------------------------------------
__global__ __launch_bounds__(256) void gemm_mfma_k(
    const float* __restrict__ A, const unsigned short* __restrict__ Wt,
    const float* __restrict__ bias, float* __restrict__ C,
    int M, int N, int K, int lda, int flags,
    int mDiv, int mOuter, int mOff)
{
  __shared__ unsigned short Al[128 * 40];
  __shared__ unsigned short Bl[64 * 40];
  const int tid = threadIdx.x;
  const int bm = blockIdx.y * 128;
  const int bn = blockIdx.x * 64;
  const int lane = tid & 63;
  const int wv = tid >> 6;
  const int wm = (wv >> 1) * 64;
  const int wn = (wv & 1) * 32;
  const int s_row = tid >> 1;
  const int s_cb = (tid & 1) * 16;
  const int grow = bm + s_row;
  const float* Arow = nullptr;
  if (grow < M) {
    int r = grow;
    if (mDiv > 0) r = (r / mDiv) * mOuter + mOff + (r % mDiv);
    Arow = A + (size_t)r * lda;
  }
  const int b_col = tid >> 2;
  const int b_ks = (tid & 3) * 8;
  const unsigned short* Wrow = Wt + (size_t)(bn + b_col) * K + b_ks;

  f32x4 acc[4][2] = {};
  const int l15 = lane & 15;
  const int lk = (lane >> 4) * 8;

  for (int k0 = 0; k0 < K; k0 += 32) {
    unsigned abuf[8];
    if (Arow) {
      const float* p = Arow + k0 + s_cb;
      #pragma unroll
      for (int i = 0; i < 4; ++i) {
        const float4 v = *(const float4*)(p + i * 4);
        abuf[i * 2 + 0] = f2bf2(v.x, v.y);
        abuf[i * 2 + 1] = f2bf2(v.z, v.w);
      }
    } else {
      #pragma unroll
      for (int i = 0; i < 8; ++i) abuf[i] = 0;
    }
    *(uint4*)&Al[s_row * 40 + s_cb] = *(uint4*)&abuf[0];
    *(uint4*)&Al[s_row * 40 + s_cb + 8] = *(uint4*)&abuf[4];
    *(bf16x8*)&Bl[b_col * 40 + b_ks] = *(const bf16x8*)(Wrow + k0);
    __syncthreads();
    bf16x8 af[4], bfr[2];
    #pragma unroll
    for (int m = 0; m < 4; ++m)
      af[m] = *(const bf16x8*)&Al[(wm + m * 16 + l15) * 40 + lk];
    #pragma unroll
    for (int n = 0; n < 2; ++n)
      bfr[n] = *(const bf16x8*)&Bl[(wn + n * 16 + l15) * 40 + lk];
    #pragma unroll
    for (int m = 0; m < 4; ++m)
      #pragma unroll
      for (int n = 0; n < 2; ++n)
        acc[m][n] = __builtin_amdgcn_mfma_f32_16x16x32_bf16(af[m], bfr[n], acc[m][n], 0, 0, 0);
    __syncthreads();
  }
  const int r4 = (lane >> 4) * 4;
  #pragma unroll
  for (int m = 0; m < 4; ++m) {
    #pragma unroll
    for (int n = 0; n < 2; ++n) {
      const int col = bn + wn + n * 16 + l15;
      const float bv = bias ? bias[col] : 0.f;
      #pragma unroll
      for (int r = 0; r < 4; ++r) {
        const int row = bm + wm + m * 16 + r4 + r;
        if (row >= M) continue;
        float v = acc[m][n][r] + bv;
        float* cp = C + (size_t)row * N + col;
        if (flags & 1) v += *cp;
        if (flags & 2) v = fmaxf(v, 0.f);
        *cp = v;
      }
    }
  }
}

// ---------------------------------------------------------------------------
// fp32 fallback GEMM (used only for K=8 edge-emb GEMM)
// ---------------------------------------------------------------------------
__global__ __launch_bounds__(256) void gemm_k(
    const float* __restrict__ A, const float* __restrict__ W,
    const float* __restrict__ bias, float* __restrict__ C,
    int M, int N, int K, int lda, int flags)
{
  __shared__ float As[16][68];
  __shared__ float Ws[16][64];
  const int tid = threadIdx.x;
  const int bm = blockIdx.y * 64;
  const int bn = blockIdx.x * 64;
  const int tx = tid & 15;
  const int ty = tid >> 4;
  const int ar = tid >> 2;
  const int ac = (tid & 3) << 2;
  const int wr = tid >> 4;
  const int wc = (tid & 15) << 2;
  const int grow = bm + ar;
  const float* Arow = (grow < M) ? A + (size_t)grow * lda : nullptr;
  float acc[4][4] = {};
  for (int k0 = 0; k0 < K; k0 += 16) {
    float4 av = make_float4(0.f, 0.f, 0.f, 0.f);
    if (Arow) {
      av.x = (k0 + ac + 0 < K) ? Arow[k0 + ac + 0] : 0.f;
      av.y = (k0 + ac + 1 < K) ? Arow[k0 + ac + 1] : 0.f;
      av.z = (k0 + ac + 2 < K) ? Arow[k0 + ac + 2] : 0.f;
      av.w = (k0 + ac + 3 < K) ? Arow[k0 + ac + 3] : 0.f;
    }
    As[ac + 0][ar] = av.x;
    As[ac + 1][ar] = av.y;
    As[ac + 2][ar] = av.z;
    As[ac + 3][ar] = av.w;
    float4 wv = make_float4(0.f, 0.f, 0.f, 0.f);
    if (k0 + wr < K) {
      const int gc = bn + wc;
      const float* wp = W + (size_t)(k0 + wr) * N + gc;
      wv.x = (gc + 0 < N) ? wp[0] : 0.f;
      wv.y = (gc + 1 < N) ? wp[1] : 0.f;
      wv.z = (gc + 2 < N) ? wp[2] : 0.f;
      wv.w = (gc + 3 < N) ? wp[3] : 0.f;
    }
    *(float4*)&Ws[wr][wc] = wv;
    __syncthreads();
    #pragma unroll
    for (int kk = 0; kk < 16; ++kk) {
      const float4 a = *(const float4*)&As[kk][ty << 2];
      const float4 b = *(const float4*)&Ws[kk][tx << 2];
      acc[0][0] += a.x * b.x; acc[0][1] += a.x * b.y; acc[0][2] += a.x * b.z; acc[0][3] += a.x * b.w;
      acc[1][0] += a.y * b.x; acc[1][1] += a.y * b.y; acc[1][2] += a.y * b.z; acc[1][3] += a.y * b.w;
      acc[2][0] += a.z * b.x; acc[2][1] += a.z * b.y; acc[2][2] += a.z * b.z; acc[2][3] += a.z * b.w;
      acc[3][0] += a.w * b.x; acc[3][1] += a.w * b.y; acc[3][2] += a.w * b.z; acc[3][3] += a.w * b.w;
    }
    __syncthreads();
  }
  #pragma unroll
  for (int i = 0; i < 4; ++i) {
    const int row = bm + (ty << 2) + i;
    if (row >= M) continue;
    float* crow = C + (size_t)row * N;
    #pragma unroll
    for (int j = 0; j < 4; ++j) {
      const int col = bn + (tx << 2) + j;
      if (col >= N) continue;
      float v = acc[i][j];
      if (bias) v += bias[col];
      if (flags & 1) v += crow[col];
      if (flags & 2) v = fmaxf(v, 0.f);
      crow[col] = v;
    }
  }
}

// ---------------------------------------------------------------------------
// Stage A kernels
// ---------------------------------------------------------------------------
__global__ void gather_tok_k(const float* __restrict__ env,
                             const float* __restrict__ infra,
                             const float* __restrict__ robot,
                             float* __restrict__ tok, int base)
{
  const int idx = blockIdx.x * blockDim.x + threadIdx.x;  // float4 units
  const int total4 = 12000 * 3 * 64;
  if (idx >= total4) return;
  const int flat = idx << 2;
  const int d = flat & 255;
  const int rs = flat >> 8;
  const int s = rs % 3;
  const int tn = rs / 3;
  const float* srcp = (s == 0 ? env : (s == 1 ? infra : robot));
  const float4 v = *(const float4*)(srcp + ((size_t)(base + tn)) * 256 + d);
  *(float4*)(tok + (size_t)flat) = v;
}

// per-(node,h): 3x3 attention, averaged over the 3 query slots -> obar
__global__ void attn_avg_k(const float* __restrict__ qkv, float* __restrict__ obar,
                           int nodes)
{
  const int idx = blockIdx.x * blockDim.x + threadIdx.x;
  if (idx >= nodes * 8) return;
  const int node = idx >> 3, h = idx & 7;
  const float* base = qkv + (size_t)node * 2304 + h * 32;
  float att[3][3];
  #pragma unroll
  for (int s = 0; s < 3; ++s) {
    const float* q = base + s * 768;
    #pragma unroll
    for (int t = 0; t < 3; ++t) {
      const float* k = base + t * 768 + 256;
      float d = 0.f;
      #pragma unroll
      for (int i = 0; i < 32; i += 4) {
        const float4 qv = *(const float4*)(q + i);
        const float4 kv = *(const float4*)(k + i);
        d += qv.x * kv.x + qv.y * kv.y + qv.z * kv.z + qv.w * kv.w;
      }
      att[s][t] = d * 0.17677669529663687f;
    }
  }
  float cs[3] = {0.f, 0.f, 0.f};
  #pragma unroll
  for (int s = 0; s < 3; ++s) {
    const float m = fmaxf(att[s][0], fmaxf(att[s][1], att[s][2]));
    const float e0 = expf(att[s][0] - m);
    const float e1 = expf(att[s][1] - m);
    const float e2 = expf(att[s][2] - m);
    const float inv = (1.f / 3.f) / (e0 + e1 + e2);
    cs[0] += e0 * inv; cs[1] += e1 * inv; cs[2] += e2 * inv;
  }
  float* op = obar + (size_t)node * 256 + h * 32;
  #pragma unroll
  for (int i = 0; i < 32; i += 4) {
    float4 o = make_float4(0.f, 0.f, 0.f, 0.f);
    #pragma unroll
    for (int t = 0; t < 3; ++t) {
      const float4 v = *(const float4*)(base + t * 768 + 512 + i);
      o.x += cs[t] * v.x; o.y += cs[t] * v.y; o.z += cs[t] * v.z; o.w += cs[t] * v.w;
    }
    *(float4*)(op + i) = o;
  }
}

// plain LayerNorm per row. 1 wave per row.
__global__ __launch_bounds__(64) void ln_k(
    const float* __restrict__ in, const float* __restrict__ g,
    const float* __restrict__ bta, float* __restrict__ outp)
{
  const int row = blockIdx.x;
  const int d0 = threadIdx.x << 2;
  const float4 a = *(const float4*)(in + (size_t)row * 256 + d0);
  float x[4] = { a.x, a.y, a.z, a.w };
  float s = x[0] + x[1] + x[2] + x[3];
  s = wred_(s);
  const float mean = s * (1.f / 256.f);
  float vs = 0.f;
  #pragma unroll
  for (int i = 0; i < 4; ++i) { const float dd = x[i] - mean; vs += dd * dd; }
  vs = wred_(vs);
  const float inv = 1.0f / sqrtf(vs * (1.f / 256.f) + 1e-5f);
  const float4 gv = *(const float4*)(g + d0);
  const float4 bv = *(const float4*)(bta + d0);
  float4 o;
  o.x = (x[0] - mean) * inv * gv.x + bv.x;
  o.y = (x[1] - mean) * inv * gv.y + bv.y;
  o.z = (x[2] - mean) * inv * gv.z + bv.z;
  o.w = (x[3] - mean) * inv * gv.w + bv.w;
  *(float4*)(outp + (size_t)row * 256 + d0) = o;
}

// ---------------------------------------------------------------------------
// GAT kernels
// ---------------------------------------------------------------------------
__global__ void alphas_k(const float* __restrict__ xw, const float* __restrict__ as,
                         const float* __restrict__ ad, float* __restrict__ sal,
                         float* __restrict__ dal, int rows)
{
  const int idx = blockIdx.x * blockDim.x + threadIdx.x;
  if (idx >= rows * 8) return;
  const int row = idx >> 3, h = idx & 7;
  const float* x = xw + (size_t)row * 256 + h * 32;
  const float* a1 = as + h * 32;
  const float* a2 = ad + h * 32;
  float s = 0.f, d = 0.f;
  #pragma unroll
  for (int i = 0; i < 32; ++i) { s += x[i] * a1[i]; d += x[i] * a2[i]; }
  sal[idx] = s; dal[idx] = d;
}

__global__ void elog_k(const float* __restrict__ ew, const float* __restrict__ ae,
                       float* __restrict__ el, int rows)
{
  const int idx = blockIdx.x * blockDim.x + threadIdx.x;
  if (idx >= rows * 8) return;
  const int row = idx >> 3, h = idx & 7;
  const float* x = ew + (size_t)row * 256 + h * 32;
  const float* a1 = ae + h * 32;
  float s = 0.f;
  #pragma unroll
  for (int i = 0; i < 32; ++i) s += x[i] * a1[i];
  el[idx] = s;
}

// Fused GAT aggregation: one wave per (b,node). Online softmax over incoming
// edges (CSR), accumulate (xw[src]+ew[e])*w, single coalesced write. No atomics.
__global__ __launch_bounds__(256) void gat_k(
    const float* __restrict__ xw, const float* __restrict__ ew,
    const float* __restrict__ sal, const float* __restrict__ dal,
    const float* __restrict__ el, const int* __restrict__ roff,
    const int* __restrict__ eord, const int* __restrict__ srcArr,
    float* __restrict__ outp, int outStride)
{
  const int wid = blockIdx.x * 4 + (threadIdx.x >> 6);
  if (wid >= B_ * N_) return;
  const int b = wid / N_;
  const int n = wid - b * N_;
  const int lane = threadIdx.x & 63;
  const int h = lane >> 3;
  const int d0 = lane << 2;
  const float dal_h = dal[(size_t)wid * 8 + h];
  const int p0 = roff[n], p1 = roff[n + 1];
  float m = -1e30f, s = 0.f;
  float4 acc = make_float4(0.f, 0.f, 0.f, 0.f);
  for (int p = p0; p < p1; ++p) {
    const int e = eord[p];
    const int sc = srcArr[e];
    float lg = sal[((size_t)b * N_ + sc) * 8 + h] + dal_h + el[((size_t)b * E_ + e) * 8 + h];
    lg = lg > 0.f ? lg : 0.2f * lg;
    const float mn = fmaxf(m, lg);
    const float scale = expf(m - mn);
    const float w = expf(lg - mn);
    s = s * scale + w;
    const float4 xv = *(const float4*)(xw + ((size_t)b * N_ + sc) * 256 + d0);
    const float4 ev = *(const float4*)(ew + ((size_t)b * E_ + e) * 256 + d0);
    acc.x = acc.x * scale + w * (xv.x + ev.x);
    acc.y = acc.y * scale + w * (xv.y + ev.y);
    acc.z = acc.z * scale + w * (xv.z + ev.z);
    acc.w = acc.w * scale + w * (xv.w + ev.w);
    m = mn;
  }
  const float inv = 1.0f / (s + 1e-16f);
  float4 o = make_float4(acc.x * inv, acc.y * inv, acc.z * inv, acc.w * inv);
  *(float4*)(outp + (size_t)wid * outStride + d0) = o;
}

// LSTM cell pointwise; writes h into both h[] and ghcat[:,256:512]
__global__ __launch_bounds__(256) void lstm_k(const float* __restrict__ gates,
                                              float* __restrict__ h, float* __restrict__ c,
                                              float* __restrict__ ghcat)
{
  const int row = blockIdx.x;
  const int d = threadIdx.x;
  const float* g = gates + (size_t)row * 1024;
  const float i_ = sigm_(g[d]);
  const float f_ = sigm_(g[256 + d]);
  const float gg = tanhf(g[512 + d]);
  const float o_ = sigm_(g[768 + d]);
  const size_t idx = (size_t)row * 256 + d;
  const float cn = f_ * c[idx] + i_ * gg;
  c[idx] = cn;
  const float hn = o_ * tanhf(cn);
  h[idx] = hn;
  ghcat[(size_t)row * 512 + 256 + d] = hn;
}

__global__ __launch_bounds__(64) void resln_k(float* __restrict__ h,
                                              const float* __restrict__ add,
                                              const float* __restrict__ g,
                                              const float* __restrict__ bta)
{
  const int row = blockIdx.x;
  const int d0 = threadIdx.x << 2;
  float* hp = h + (size_t)row * 256;
  const float4 hv = *(const float4*)(hp + d0);
  const float4 av = *(const float4*)(add + (size_t)row * 256 + d0);
  float x[4] = { hv.x + av.x, hv.y + av.y, hv.z + av.z, hv.w + av.w };
  float s = x[0] + x[1] + x[2] + x[3];
  s = wred_(s);
  const float mean = s * (1.f / 256.f);
  float vs = 0.f;
  #pragma unroll
  for (int i = 0; i < 4; ++i) { const float dd = x[i] - mean; vs += dd * dd; }
  vs = wred_(vs);
  const float inv = 1.0f / sqrtf(vs * (1.f / 256.f) + 1e-5f);
  const float4 gv = *(const float4*)(g + d0);
  const float4 bv = *(const float4*)(bta + d0);
  float4 o;
  o.x = (x[0] - mean) * inv * gv.x + bv.x;
  o.y = (x[1] - mean) * inv * gv.y + bv.y;
  o.z = (x[2] - mean) * inv * gv.z + bv.z;
  o.w = (x[3] - mean) * inv * gv.w + bv.w;
  *(float4*)(hp + d0) = o;
}

// ---------------------------------------------------------------------------
// Head kernels
// ---------------------------------------------------------------------------
__global__ void nh2_k(const float* __restrict__ hidden, const float* __restrict__ w2,
                      const float* __restrict__ b2, float* __restrict__ outp)
{
  const int idx = blockIdx.x * blockDim.x + threadIdx.x;
  if (idx >= B_ * N_ * 7) return;
  const int row = idx / 7, j = idx % 7;
  const float* hp = hidden + (size_t)row * 448 + j * 64;
  const float* wp = w2 + j * 64;
  float a = 0.f;
  #pragma unroll
  for (int u = 0; u < 64; ++u) a += hp[u] * wp[u];
  a += b2[j];
  if (j == 0 || j == 6) a = sigm_(a);
  else if (j == 1) a = softplus_(a);
  const int b = row / N_, n = row % N_;
  outp[(size_t)b * OUTS_ + n * 7 + j] = a;
}

__global__ __launch_bounds__(256) void hglob_k(const float* __restrict__ h, float* __restrict__ hg)
{
  const int b = blockIdx.x;
  const int d = threadIdx.x;
  float s = 0.f;
  for (int n = 0; n < N_; ++n) s += h[((size_t)(b * N_ + n)) * 256 + d];
  hg[b * 256 + d] = s * (1.f / (float)N_);
}

__global__ __launch_bounds__(64) void freq_k(const float* __restrict__ hg,
                                             const float* __restrict__ w1, const float* __restrict__ b1,
                                             const float* __restrict__ w2, const float* __restrict__ b2,
                                             float* __restrict__ outp)
{
  const int b = blockIdx.x;
  const int u = threadIdx.x;
  float a = b1[u];
  for (int k = 0; k < 256; ++k) a += hg[b * 256 + k] * w1[k * 64 + u];
  a = fmaxf(a, 0.f) * w2[u];
  a = wred_(a);
  if (u == 0) outp[(size_t)b * OUTS_ + 45000] = a + b2[0];
}

__global__ void ef_k(const float* __restrict__ h, const int* __restrict__ src,
                     const int* __restrict__ dst, float* __restrict__ ef)
{
  const int idx = blockIdx.x * blockDim.x + threadIdx.x;  // float4 units
  if (idx >= B_ * E_ * 128) return;
  const int q = idx & 127;
  const int row = idx >> 7;
  const int b = row / E_, e = row % E_;
  const int d = q << 2;
  const float* p = (d < 256)
      ? h + ((size_t)(b * N_ + src[e])) * 256 + d
      : h + ((size_t)(b * N_ + dst[e])) * 256 + (d - 256);
  *(float4*)(ef + (size_t)row * 512 + d) = *(const float4*)p;
}

__global__ void eh2_k(const float* __restrict__ hidden, const float* __restrict__ w2,
                      const float* __restrict__ b2, float* __restrict__ outp)
{
  const int idx = blockIdx.x * blockDim.x + threadIdx.x;
  if (idx >= 2 * B_ * E_) return;
  const int jj = idx / (B_ * E_);
  const int r = idx - jj * (B_ * E_);
  const int b = r / E_, e = r % E_;
  const float* hp = hidden + (size_t)r * 128 + jj * 64;
  const float* wp = w2 + jj * 64;
  float a = 0.f;
  #pragma unroll
  for (int u = 0; u < 64; ++u) a += hp[u] * wp[u];
  a += b2[jj];
  outp[(size_t)b * OUTS_ + 21000 + jj * 12000 + e] = a;
}

// ---------------------------------------------------------------------------
extern "C" void kernel_launch(void* const* d_in, const int* in_sizes, int n_in,
                              void* d_out, int out_size, void* d_ws, size_t ws_size,
                              hipStream_t stream)
{
  const float* env      = (const float*)d_in[0];
  const float* infra    = (const float*)d_in[1];
  const float* robot    = (const float*)d_in[2];
  const float* edgeattr = (const float*)d_in[3];
  const int*   eidx     = (const int*)d_in[4];
  const float* wqkv     = (const float*)d_in[5];
  const float* bqkv     = (const float*)d_in[6];
  const float* wo       = (const float*)d_in[7];
  const float* bo       = (const float*)d_in[8];
  const float* lnf_g    = (const float*)d_in[9];
  const float* lnf_b    = (const float*)d_in[10];
  const float* we_emb   = (const float*)d_in[11];
  const float* be_emb   = (const float*)d_in[12];
  const float* tg_W     = (const float*)d_in[13];
  const float* tg_We    = (const float*)d_in[14];
  const float* tg_asrc  = (const float*)d_in[15];
  const float* tg_adst  = (const float*)d_in[16];
  const float* tg_aedge = (const float*)d_in[17];
  const float* w_ih     = (const float*)d_in[18];
  const float* w_hh     = (const float*)d_in[19];
  const float* b_lstm   = (const float*)d_in[20];
  const float* g_W      = (const float*)d_in[21];
  const float* g_We     = (const float*)d_in[22];
  const float* g_asrc   = (const float*)d_in[23];
  const float* g_adst   = (const float*)d_in[24];
  const float* g_aedge  = (const float*)d_in[25];
  const float* g_lng    = (const float*)d_in[26];
  const float* g_lnb    = (const float*)d_in[27];
  const float* hn_w1    = (const float*)d_in[28];
  const float* hn_b1    = (const float*)d_in[29];
  const float* hn_w2    = (const float*)d_in[30];
  const float* hn_b2    = (const float*)d_in[31];
  const float* he_w1    = (const float*)d_in[32];
  const float* he_b1    = (const float*)d_in[33];
  const float* he_w2    = (const float*)d_in[34];
  const float* he_b2    = (const float*)d_in[35];

  const int* src = eidx;
  const int* dst = eidx + E_;
  float* outp = (float*)d_out;
  float* ws = (float*)d_ws;

  // ---- workspace layout (floats) ----
  const size_t A0 = 24576000;                 // fseq size (B*T*N*256)
  float* fseq = ws;
  // stage A scratch:
  float* tok   = ws + A0;                     //  9,216,000
  float* qkv   = ws + A0 + 9216000;           // 27,648,000
  float* obarA = ws + A0 + 36864000;          // 24,576,000 (all 96000 rows)
  float* tmpA  = qkv;                         // 24,576,000 (reuse qkv region)
  // stage B aliases (stage A scratch dead):
  float* eemb   = ws + A0;                    // 12,288,000
  float* ewtg   = ws + A0 + 12288000;         // 12,288,000
  float* elogtg = ws + A0 + 24576000;         //    384,000
  float* h      = ws + A0 + 24960000;         //  3,072,000
  float* c      = ws + A0 + 28032000;         //  3,072,000
  float* xw     = ws + A0 + 31104000;         //  3,072,000
  float* sal    = ws + A0 + 34176000;         //     96,000
  float* dal    = ws + A0 + 34272000;         //     96,000
  float* gat    = ws + A0 + 34368000;         //  3,072,000
  float* ghcat  = ws + A0 + 37440000;         //  6,144,000 ([12000][512])
  float* gates  = ws + A0 + 43584000;         // 12,288,000
  float* ewl    = ws + A0 + 55872000;         // 12,288,000
  float* elogl  = ws + A0 + 68160000;         //    384,000
  float* hg     = ws + A0 + 68544000;         //      1,024
  int*   ideg   = (int*)(ws + A0 + 68560000); //      3,000 ints
  int*   iroff  = ideg + 3008;                //      3,001 ints
  int*   ieord  = iroff + 3008;               //     12,000 ints
  // end-phase aliases:
  float* ef     = ws + A0;                    // 24,576,000 (over eemb/ewtg)
  float* hide   = gates;                      //  6,144,000 ([B*E][128])
  float* hidn   = ewl;                        //  5,376,000 ([B*N][448])
  // bf16 transposed weights
  unsigned short* wtb = (unsigned short*)(ws + 94000000);
  unsigned short* wt_qkv = wtb;               // 196,608
  unsigned short* wt_wo  = wtb + 196608;      //  65,536
  unsigned short* wt_tgW = wtb + 262144;      //  65,536
  unsigned short* wt_tgWe= wtb + 327680;      //  65,536
  unsigned short* wt_cat = wtb + 393216;      // 524,288 ([1024][512] = [wih;whh])
  unsigned short* wt_gW  = wtb + 917504;      // 196,608 (3 layers)
  unsigned short* wt_gWe = wtb + 1114112;     // 196,608
  unsigned short* wt_hn  = wtb + 1310720;     // 114,688 (7 heads -> [448][256])
  unsigned short* wt_he  = wtb + 1425408;     //  65,536 (2 heads -> [128][512])

  auto mgemm = [&](const float* A, const unsigned short* Wt, const float* bias,
                   float* C, int M, int N, int K, int lda, int flags,
                   int mDiv = 0, int mOuter = 0, int mOff = 0) {
    dim3 grid(N / 64, (M + 127) / 128);
    gemm_mfma_k<<<grid, dim3(256), 0, stream>>>(A, Wt, bias, C, M, N, K, lda,
                                                flags, mDiv, mOuter, mOff);
  };
  auto cvt = [&](const float* W, unsigned short* Wt, int K, int N,
                 int dstStride = 0, int kOff = 0) {
    wt_k<<<(K * N + 255) / 256, 256, 0, stream>>>(W, Wt, K, N,
                                                  dstStride ? dstStride : K, kOff);
  };

  // ---- weight convert+transpose (bf16) ----
  cvt(wqkv, wt_qkv, 256, 768);
  cvt(wo, wt_wo, 256, 256);
  cvt(tg_W, wt_tgW, 256, 256);
  cvt(tg_We, wt_tgWe, 256, 256);
  cvt(w_ih, wt_cat, 256, 1024, 512, 0);
  cvt(w_hh, wt_cat, 256, 1024, 512, 256);
  for (int l = 0; l < 3; ++l) {
    cvt(g_W + (size_t)l * 65536, wt_gW + (size_t)l * 65536, 256, 256);
    cvt(g_We + (size_t)l * 65536, wt_gWe + (size_t)l * 65536, 256, 256);
  }
  for (int j = 0; j < 7; ++j)
    cvt(hn_w1 + (size_t)j * 16384, wt_hn + (size_t)j * 16384, 256, 64);
  for (int jj = 0; jj < 2; ++jj)
    cvt(he_w1 + (size_t)jj * 32768, wt_he + (size_t)jj * 32768, 512, 64);

  // ---- CSR build (deterministic) ----
  hipMemsetAsync(ideg, 0, 3000 * sizeof(int), stream);
  hist_k<<<(E_ + 255) / 256, 256, 0, stream>>>(dst, ideg);
  scan_k<<<1, 256, 0, stream>>>(ideg, iroff);
  fill_k<<<750, 256, 0, stream>>>(dst, iroff, ieord);

  // ---------------- Stage A: token attention -> obar ----------------
  for (int b = 0; b < B_; ++b) {
    for (int half = 0; half < 2; ++half) {
      const int base = (b * T_ + half * 4) * N_;
      gather_tok_k<<<9000, 256, 0, stream>>>(env, infra, robot, tok, base);
      mgemm(tok, wt_qkv, bqkv, qkv, 36000, 768, 256, 256, 0);
      attn_avg_k<<<375, 256, 0, stream>>>(qkv, obarA + (size_t)base * 256, 12000);
    }
  }
  // fused_seq = LN(obar @ wo + bo) over all 96000 rows
  mgemm(obarA, wt_wo, bo, tmpA, 96000, 256, 256, 256, 0);
  ln_k<<<96000, 64, 0, stream>>>(tmpA, lnf_g, lnf_b, fseq);

  // ---------------- Stage B: GAT-LSTM ----------------
  hipMemsetAsync(c, 0, 12288000, stream);
  hipMemsetAsync(ghcat, 0, 24576000, stream);
  hipMemsetAsync(h, 0, 12288000, stream);

  {  // edge_emb = relu(edge_attr @ we_emb + be_emb)   (48000 x 256, K=8)
    dim3 grid(4, 750);
    gemm_k<<<grid, dim3(256), 0, stream>>>(edgeattr, we_emb, be_emb, eemb,
                                           48000, 256, 8, 8, 2);
  }
  mgemm(eemb, wt_tgWe, nullptr, ewtg, 48000, 256, 256, 256, 0);
  elog_k<<<1500, 256, 0, stream>>>(ewtg, tg_aedge, elogtg, 48000);

  for (int t = 0; t < T_; ++t) {
    mgemm(fseq, wt_tgW, nullptr, xw, 12000, 256, 256, 256, 0, N_, T_ * N_, t * N_);
    alphas_k<<<375, 256, 0, stream>>>(xw, tg_asrc, tg_adst, sal, dal, 12000);
    gat_k<<<3000, 256, 0, stream>>>(xw, ewtg, sal, dal, elogtg, iroff, ieord, src,
                                    ghcat, 512);
    mgemm(ghcat, wt_cat, b_lstm, gates, 12000, 1024, 512, 512, 0);
    lstm_k<<<12000, 256, 0, stream>>>(gates, h, c, ghcat);
  }

  // ---------------- 3 GAT layers with residual LN ----------------
  for (int l = 0; l < 3; ++l) {
    mgemm(eemb, wt_gWe + (size_t)l * 65536, nullptr, ewl, 48000, 256, 256, 256, 0);
    elog_k<<<1500, 256, 0, stream>>>(ewl, g_aedge + l * 256, elogl, 48000);
    mgemm(h, wt_gW + (size_t)l * 65536, nullptr, xw, 12000, 256, 256, 256, 0);
    alphas_k<<<375, 256, 0, stream>>>(xw, g_asrc + l * 256, g_adst + l * 256, sal, dal, 12000);
    gat_k<<<3000, 256, 0, stream>>>(xw, ewl, sal, dal, elogl, iroff, ieord, src,
                                    gat, 256);
    resln_k<<<12000, 64, 0, stream>>>(h, gat, g_lng + l * 256, g_lnb + l * 256);
  }

  // ---------------- Heads ----------------
  mgemm(h, wt_hn, hn_b1, hidn, 12000, 448, 256, 256, 2);
  nh2_k<<<(84000 + 255) / 256, 256, 0, stream>>>(hidn, hn_w2, hn_b2, outp);

  hglob_k<<<4, 256, 0, stream>>>(h, hg);
  freq_k<<<4, 64, 0, stream>>>(hg, hn_w1 + 7 * 16384, hn_b1 + 7 * 64,
                               hn_w2 + 7 * 64, hn_b2 + 7, outp);

  ef_k<<<24000, 256, 0, stream>>>(h, src, dst, ef);
  mgemm(ef, wt_he, he_b1, hide, 48000, 128, 512, 512, 2);
  eh2_k<<<(96000 + 255) / 256, 256, 0, stream>>>(hide, he_w2, he_b2, outp);
}

// Round 5
// 2576.317 us; speedup vs baseline: 5.1862x; 1.0381x over previous
//
#include <hip/hip_runtime.h>
#include <hip/hip_bf16.h>
#include <math.h>

#define DEV __device__ __forceinline__

namespace {
constexpr int B_ = 4, T_ = 8, N_ = 3000, E_ = 12000;
constexpr int OUTS_ = 45001;  // per-batch output stride: N*7 + E + E + 1
}

using bf16x8 = __attribute__((ext_vector_type(8))) short;
using f32x4  = __attribute__((ext_vector_type(4))) float;

DEV float sigm_(float x) { return 1.0f / (1.0f + expf(-x)); }
DEV float softplus_(float x) { return fmaxf(x, 0.0f) + log1pf(expf(-fabsf(x))); }
DEV float wred_(float v) {
  #pragma unroll
  for (int o = 32; o > 0; o >>= 1) v += __shfl_xor(v, o, 64);
  return v;
}
DEV unsigned short f2bf(float x) {  // RNE fp32->bf16
  unsigned u = __float_as_uint(x);
  return (unsigned short)((u + 0x7FFFu + ((u >> 16) & 1u)) >> 16);
}
DEV unsigned f2bf2(float a, float b) {
  return (unsigned)f2bf(a) | ((unsigned)f2bf(b) << 16);
}

// ---------------------------------------------------------------------------
// Batched weight transpose+convert: L matrices [K][N] packed contiguously ->
// per-matrix [N][K] bf16 packed contiguously.
// ---------------------------------------------------------------------------
__global__ void wtb_k(const float* __restrict__ W, unsigned short* __restrict__ Wt,
                      int K, int N, int total)
{
  const int idx = blockIdx.x * blockDim.x + threadIdx.x;
  if (idx >= total) return;
  const int kn = K * N;
  const int l = idx / kn;
  const int r = idx - l * kn;
  const int k = r / N, n = r - k * N;
  Wt[(size_t)l * kn + (size_t)n * K + k] = f2bf(W[idx]);
}

// ---------------------------------------------------------------------------
// CSR build (deterministic)
// ---------------------------------------------------------------------------
__global__ void hist_k(const int* __restrict__ dst, int* __restrict__ deg)
{
  const int e = blockIdx.x * blockDim.x + threadIdx.x;
  if (e < E_) atomicAdd(&deg[dst[e]], 1);
}

__global__ __launch_bounds__(256) void scan_k(const int* __restrict__ deg,
                                              int* __restrict__ roff)
{
  __shared__ int part[256];
  const int t = threadIdx.x;
  int loc[12];
  int s = 0;
  #pragma unroll
  for (int i = 0; i < 12; ++i) {
    const int n = t * 12 + i;
    loc[i] = s;
    s += (n < N_) ? deg[n] : 0;
  }
  part[t] = s;
  __syncthreads();
  if (t == 0) {
    int run = 0;
    for (int i = 0; i < 256; ++i) { const int v = part[i]; part[i] = run; run += v; }
  }
  __syncthreads();
  const int base = part[t];
  #pragma unroll
  for (int i = 0; i < 12; ++i) {
    const int n = t * 12 + i;
    if (n < N_) roff[n] = base + loc[i];
  }
  if (t == 0) roff[N_] = E_;
}

__global__ __launch_bounds__(256) void fill_k(const int* __restrict__ dst,
                                              const int* __restrict__ roff,
                                              int* __restrict__ eord)
{
  const int n = blockIdx.x * 4 + (threadIdx.x >> 6);
  if (n >= N_) return;
  const int lane = threadIdx.x & 63;
  const unsigned long long ltm = (1ull << lane) - 1ull;
  int cnt = roff[n];
  for (int c = 0; c < E_; c += 64) {
    const int e = c + lane;
    const bool m = (e < E_) && (dst[e] == n);
    const unsigned long long mask = __ballot(m);
    if (m) eord[cnt + __popcll(mask & ltm)] = e;
    cnt += __popcll(mask);
  }
}

// ---------------------------------------------------------------------------
// MFMA bf16 GEMM: C[M,N] = A[M,K](fp32) @ W[K,N] via Wt(bf16,[N][K])
// (+bias) (+C if flags&1) (relu if flags&2). K%32==0, N%64==0.
// B row stride == K (Wt must be dense [N][K]).
// C index = row*ldc + coff + col.
// Optional A logical-row remap: phys = (r/mDiv)*mOuter + mOff + r%mDiv
// Tile: 128x64, 4 waves each 64x32 (4x2 frags of 16x16), BK=32.
// ---------------------------------------------------------------------------
__global__ __launch_bounds__(256) void gemm_mfma_k(
    const float* __restrict__ A, const unsigned short* __restrict__ Wt,
    const float* __restrict__ bias, float* __restrict__ C,
    int M, int N, int K, int lda, int ldc, int coff, int flags,
    int mDiv, int mOuter, int mOff)
{
  __shared__ unsigned short Al[128 * 40];
  __shared__ unsigned short Bl[64 * 40];
  const int tid = threadIdx.x;
  const int bm = blockIdx.y * 128;
  const int bn = blockIdx.x * 64;
  const int lane = tid & 63;
  const int wv = tid >> 6;
  const int wm = (wv >> 1) * 64;
  const int wn = (wv & 1) * 32;
  const int s_row = tid >> 1;
  const int s_cb = (tid & 1) * 16;
  const int grow = bm + s_row;
  const float* Arow = nullptr;
  if (grow < M) {
    int r = grow;
    if (mDiv > 0) r = (r / mDiv) * mOuter + mOff + (r % mDiv);
    Arow = A + (size_t)r * lda;
  }
  const int b_col = tid >> 2;
  const int b_ks = (tid & 3) * 8;
  const unsigned short* Wrow = Wt + (size_t)(bn + b_col) * K + b_ks;

  f32x4 acc[4][2] = {};
  const int l15 = lane & 15;
  const int lk = (lane >> 4) * 8;

  for (int k0 = 0; k0 < K; k0 += 32) {
    unsigned abuf[8];
    if (Arow) {
      const float* p = Arow + k0 + s_cb;
      #pragma unroll
      for (int i = 0; i < 4; ++i) {
        const float4 v = *(const float4*)(p + i * 4);
        abuf[i * 2 + 0] = f2bf2(v.x, v.y);
        abuf[i * 2 + 1] = f2bf2(v.z, v.w);
      }
    } else {
      #pragma unroll
      for (int i = 0; i < 8; ++i) abuf[i] = 0;
    }
    *(uint4*)&Al[s_row * 40 + s_cb] = *(uint4*)&abuf[0];
    *(uint4*)&Al[s_row * 40 + s_cb + 8] = *(uint4*)&abuf[4];
    *(bf16x8*)&Bl[b_col * 40 + b_ks] = *(const bf16x8*)(Wrow + k0);
    __syncthreads();
    bf16x8 af[4], bfr[2];
    #pragma unroll
    for (int m = 0; m < 4; ++m)
      af[m] = *(const bf16x8*)&Al[(wm + m * 16 + l15) * 40 + lk];
    #pragma unroll
    for (int n = 0; n < 2; ++n)
      bfr[n] = *(const bf16x8*)&Bl[(wn + n * 16 + l15) * 40 + lk];
    #pragma unroll
    for (int m = 0; m < 4; ++m)
      #pragma unroll
      for (int n = 0; n < 2; ++n)
        acc[m][n] = __builtin_amdgcn_mfma_f32_16x16x32_bf16(af[m], bfr[n], acc[m][n], 0, 0, 0);
    __syncthreads();
  }
  const int r4 = (lane >> 4) * 4;
  #pragma unroll
  for (int m = 0; m < 4; ++m) {
    #pragma unroll
    for (int n = 0; n < 2; ++n) {
      const int col = bn + wn + n * 16 + l15;
      const float bv = bias ? bias[col] : 0.f;
      #pragma unroll
      for (int r = 0; r < 4; ++r) {
        const int row = bm + wm + m * 16 + r4 + r;
        if (row >= M) continue;
        float v = acc[m][n][r] + bv;
        float* cp = C + (size_t)row * ldc + coff + col;
        if (flags & 1) v += *cp;
        if (flags & 2) v = fmaxf(v, 0.f);
        *cp = v;
      }
    }
  }
}

// ---------------------------------------------------------------------------
// fp32 fallback GEMM (used only for K=8 edge-emb GEMM)
// ---------------------------------------------------------------------------
__global__ __launch_bounds__(256) void gemm_k(
    const float* __restrict__ A, const float* __restrict__ W,
    const float* __restrict__ bias, float* __restrict__ C,
    int M, int N, int K, int lda, int flags)
{
  __shared__ float As[16][68];
  __shared__ float Ws[16][64];
  const int tid = threadIdx.x;
  const int bm = blockIdx.y * 64;
  const int bn = blockIdx.x * 64;
  const int tx = tid & 15;
  const int ty = tid >> 4;
  const int ar = tid >> 2;
  const int ac = (tid & 3) << 2;
  const int wr = tid >> 4;
  const int wc = (tid & 15) << 2;
  const int grow = bm + ar;
  const float* Arow = (grow < M) ? A + (size_t)grow * lda : nullptr;
  float acc[4][4] = {};
  for (int k0 = 0; k0 < K; k0 += 16) {
    float4 av = make_float4(0.f, 0.f, 0.f, 0.f);
    if (Arow) {
      av.x = (k0 + ac + 0 < K) ? Arow[k0 + ac + 0] : 0.f;
      av.y = (k0 + ac + 1 < K) ? Arow[k0 + ac + 1] : 0.f;
      av.z = (k0 + ac + 2 < K) ? Arow[k0 + ac + 2] : 0.f;
      av.w = (k0 + ac + 3 < K) ? Arow[k0 + ac + 3] : 0.f;
    }
    As[ac + 0][ar] = av.x;
    As[ac + 1][ar] = av.y;
    As[ac + 2][ar] = av.z;
    As[ac + 3][ar] = av.w;
    float4 wv = make_float4(0.f, 0.f, 0.f, 0.f);
    if (k0 + wr < K) {
      const int gc = bn + wc;
      const float* wp = W + (size_t)(k0 + wr) * N + gc;
      wv.x = (gc + 0 < N) ? wp[0] : 0.f;
      wv.y = (gc + 1 < N) ? wp[1] : 0.f;
      wv.z = (gc + 2 < N) ? wp[2] : 0.f;
      wv.w = (gc + 3 < N) ? wp[3] : 0.f;
    }
    *(float4*)&Ws[wr][wc] = wv;
    __syncthreads();
    #pragma unroll
    for (int kk = 0; kk < 16; ++kk) {
      const float4 a = *(const float4*)&As[kk][ty << 2];
      const float4 b = *(const float4*)&Ws[kk][tx << 2];
      acc[0][0] += a.x * b.x; acc[0][1] += a.x * b.y; acc[0][2] += a.x * b.z; acc[0][3] += a.x * b.w;
      acc[1][0] += a.y * b.x; acc[1][1] += a.y * b.y; acc[1][2] += a.y * b.z; acc[1][3] += a.y * b.w;
      acc[2][0] += a.z * b.x; acc[2][1] += a.z * b.y; acc[2][2] += a.z * b.z; acc[2][3] += a.z * b.w;
      acc[3][0] += a.w * b.x; acc[3][1] += a.w * b.y; acc[3][2] += a.w * b.z; acc[3][3] += a.w * b.w;
    }
    __syncthreads();
  }
  #pragma unroll
  for (int i = 0; i < 4; ++i) {
    const int row = bm + (ty << 2) + i;
    if (row >= M) continue;
    float* crow = C + (size_t)row * N;
    #pragma unroll
    for (int j = 0; j < 4; ++j) {
      const int col = bn + (tx << 2) + j;
      if (col >= N) continue;
      float v = acc[i][j];
      if (bias) v += bias[col];
      if (flags & 1) v += crow[col];
      if (flags & 2) v = fmaxf(v, 0.f);
      crow[col] = v;
    }
  }
}

// ---------------------------------------------------------------------------
// Stage A kernels
// ---------------------------------------------------------------------------
// per-(node,h): 3x3 attention, averaged over the 3 query slots -> obar
__global__ void attn_avg_k(const float* __restrict__ qkv, float* __restrict__ obar,
                           int nodes)
{
  const int idx = blockIdx.x * blockDim.x + threadIdx.x;
  if (idx >= nodes * 8) return;
  const int node = idx >> 3, h = idx & 7;
  const float* base = qkv + (size_t)node * 2304 + h * 32;
  float att[3][3];
  #pragma unroll
  for (int s = 0; s < 3; ++s) {
    const float* q = base + s * 768;
    #pragma unroll
    for (int t = 0; t < 3; ++t) {
      const float* k = base + t * 768 + 256;
      float d = 0.f;
      #pragma unroll
      for (int i = 0; i < 32; i += 4) {
        const float4 qv = *(const float4*)(q + i);
        const float4 kv = *(const float4*)(k + i);
        d += qv.x * kv.x + qv.y * kv.y + qv.z * kv.z + qv.w * kv.w;
      }
      att[s][t] = d * 0.17677669529663687f;
    }
  }
  float cs[3] = {0.f, 0.f, 0.f};
  #pragma unroll
  for (int s = 0; s < 3; ++s) {
    const float m = fmaxf(att[s][0], fmaxf(att[s][1], att[s][2]));
    const float e0 = expf(att[s][0] - m);
    const float e1 = expf(att[s][1] - m);
    const float e2 = expf(att[s][2] - m);
    const float inv = (1.f / 3.f) / (e0 + e1 + e2);
    cs[0] += e0 * inv; cs[1] += e1 * inv; cs[2] += e2 * inv;
  }
  float* op = obar + (size_t)node * 256 + h * 32;
  #pragma unroll
  for (int i = 0; i < 32; i += 4) {
    float4 o = make_float4(0.f, 0.f, 0.f, 0.f);
    #pragma unroll
    for (int t = 0; t < 3; ++t) {
      const float4 v = *(const float4*)(base + t * 768 + 512 + i);
      o.x += cs[t] * v.x; o.y += cs[t] * v.y; o.z += cs[t] * v.z; o.w += cs[t] * v.w;
    }
    *(float4*)(op + i) = o;
  }
}

// plain LayerNorm per row. 1 wave per row.
__global__ __launch_bounds__(64) void ln_k(
    const float* __restrict__ in, const float* __restrict__ g,
    const float* __restrict__ bta, float* __restrict__ outp)
{
  const int row = blockIdx.x;
  const int d0 = threadIdx.x << 2;
  const float4 a = *(const float4*)(in + (size_t)row * 256 + d0);
  float x[4] = { a.x, a.y, a.z, a.w };
  float s = x[0] + x[1] + x[2] + x[3];
  s = wred_(s);
  const float mean = s * (1.f / 256.f);
  float vs = 0.f;
  #pragma unroll
  for (int i = 0; i < 4; ++i) { const float dd = x[i] - mean; vs += dd * dd; }
  vs = wred_(vs);
  const float inv = 1.0f / sqrtf(vs * (1.f / 256.f) + 1e-5f);
  const float4 gv = *(const float4*)(g + d0);
  const float4 bv = *(const float4*)(bta + d0);
  float4 o;
  o.x = (x[0] - mean) * inv * gv.x + bv.x;
  o.y = (x[1] - mean) * inv * gv.y + bv.y;
  o.z = (x[2] - mean) * inv * gv.z + bv.z;
  o.w = (x[3] - mean) * inv * gv.w + bv.w;
  *(float4*)(outp + (size_t)row * 256 + d0) = o;
}

// ---------------------------------------------------------------------------
// GAT kernels
// ---------------------------------------------------------------------------
__global__ void alphas_k(const float* __restrict__ xw, const float* __restrict__ as,
                         const float* __restrict__ ad, float* __restrict__ sal,
                         float* __restrict__ dal, int rows)
{
  const int idx = blockIdx.x * blockDim.x + threadIdx.x;
  if (idx >= rows * 8) return;
  const int row = idx >> 3, h = idx & 7;
  const float* x = xw + (size_t)row * 256 + h * 32;
  const float* a1 = as + h * 32;
  const float* a2 = ad + h * 32;
  float s = 0.f, d = 0.f;
  #pragma unroll
  for (int i = 0; i < 32; ++i) { s += x[i] * a1[i]; d += x[i] * a2[i]; }
  sal[idx] = s; dal[idx] = d;
}

__global__ void elog_k(const float* __restrict__ ew, const float* __restrict__ ae,
                       float* __restrict__ el, int rows)
{
  const int idx = blockIdx.x * blockDim.x + threadIdx.x;
  if (idx >= rows * 8) return;
  const int row = idx >> 3, h = idx & 7;
  const float* x = ew + (size_t)row * 256 + h * 32;
  const float* a1 = ae + h * 32;
  float s = 0.f;
  #pragma unroll
  for (int i = 0; i < 32; ++i) s += x[i] * a1[i];
  el[idx] = s;
}

// Fused GAT aggregation: one wave per (beta,node), beta = batch-time index.
// xw/sal/dal rows are beta*N+n ; ew/el rows are (beta>>tshift)*E+e.
__global__ __launch_bounds__(256) void gat_k(
    const float* __restrict__ xw, const float* __restrict__ ew,
    const float* __restrict__ sal, const float* __restrict__ dal,
    const float* __restrict__ el, const int* __restrict__ roff,
    const int* __restrict__ eord, const int* __restrict__ srcArr,
    float* __restrict__ outp, int nwaves, int tshift)
{
  const int wid = blockIdx.x * 4 + (threadIdx.x >> 6);
  if (wid >= nwaves) return;
  const int beta = wid / N_;
  const int n = wid - beta * N_;
  const int b = beta >> tshift;
  const int lane = threadIdx.x & 63;
  const int h = lane >> 3;
  const int d0 = lane << 2;
  const float dal_h = dal[(size_t)wid * 8 + h];
  const int p0 = roff[n], p1 = roff[n + 1];
  float m = -1e30f, s = 0.f;
  float4 acc = make_float4(0.f, 0.f, 0.f, 0.f);
  for (int p = p0; p < p1; ++p) {
    const int e = eord[p];
    const int sc = srcArr[e];
    float lg = sal[((size_t)beta * N_ + sc) * 8 + h] + dal_h + el[((size_t)b * E_ + e) * 8 + h];
    lg = lg > 0.f ? lg : 0.2f * lg;
    const float mn = fmaxf(m, lg);
    const float scale = expf(m - mn);
    const float w = expf(lg - mn);
    s = s * scale + w;
    const float4 xv = *(const float4*)(xw + ((size_t)beta * N_ + sc) * 256 + d0);
    const float4 ev = *(const float4*)(ew + ((size_t)b * E_ + e) * 256 + d0);
    acc.x = acc.x * scale + w * (xv.x + ev.x);
    acc.y = acc.y * scale + w * (xv.y + ev.y);
    acc.z = acc.z * scale + w * (xv.z + ev.z);
    acc.w = acc.w * scale + w * (xv.w + ev.w);
    m = mn;
  }
  const float inv = 1.0f / (s + 1e-16f);
  float4 o = make_float4(acc.x * inv, acc.y * inv, acc.z * inv, acc.w * inv);
  *(float4*)(outp + (size_t)wid * 256 + d0) = o;
}

// LSTM cell pointwise
__global__ __launch_bounds__(256) void lstm_k(const float* __restrict__ gates,
                                              float* __restrict__ h, float* __restrict__ c)
{
  const int row = blockIdx.x;
  const int d = threadIdx.x;
  const float* g = gates + (size_t)row * 1024;
  const float i_ = sigm_(g[d]);
  const float f_ = sigm_(g[256 + d]);
  const float gg = tanhf(g[512 + d]);
  const float o_ = sigm_(g[768 + d]);
  const size_t idx = (size_t)row * 256 + d;
  const float cn = f_ * c[idx] + i_ * gg;
  c[idx] = cn;
  h[idx] = o_ * tanhf(cn);
}

__global__ __launch_bounds__(64) void resln_k(float* __restrict__ h,
                                              const float* __restrict__ add,
                                              const float* __restrict__ g,
                                              const float* __restrict__ bta)
{
  const int row = blockIdx.x;
  const int d0 = threadIdx.x << 2;
  float* hp = h + (size_t)row * 256;
  const float4 hv = *(const float4*)(hp + d0);
  const float4 av = *(const float4*)(add + (size_t)row * 256 + d0);
  float x[4] = { hv.x + av.x, hv.y + av.y, hv.z + av.z, hv.w + av.w };
  float s = x[0] + x[1] + x[2] + x[3];
  s = wred_(s);
  const float mean = s * (1.f / 256.f);
  float vs = 0.f;
  #pragma unroll
  for (int i = 0; i < 4; ++i) { const float dd = x[i] - mean; vs += dd * dd; }
  vs = wred_(vs);
  const float inv = 1.0f / sqrtf(vs * (1.f / 256.f) + 1e-5f);
  const float4 gv = *(const float4*)(g + d0);
  const float4 bv = *(const float4*)(bta + d0);
  float4 o;
  o.x = (x[0] - mean) * inv * gv.x + bv.x;
  o.y = (x[1] - mean) * inv * gv.y + bv.y;
  o.z = (x[2] - mean) * inv * gv.z + bv.z;
  o.w = (x[3] - mean) * inv * gv.w + bv.w;
  *(float4*)(hp + d0) = o;
}

// ---------------------------------------------------------------------------
// Head kernels
// ---------------------------------------------------------------------------
__global__ void nh2_k(const float* __restrict__ hidden, const float* __restrict__ w2,
                      const float* __restrict__ b2, float* __restrict__ outp)
{
  const int idx = blockIdx.x * blockDim.x + threadIdx.x;
  if (idx >= B_ * N_ * 7) return;
  const int row = idx / 7, j = idx % 7;
  const float* hp = hidden + (size_t)row * 448 + j * 64;
  const float* wp = w2 + j * 64;
  float a = 0.f;
  #pragma unroll
  for (int u = 0; u < 64; ++u) a += hp[u] * wp[u];
  a += b2[j];
  if (j == 0 || j == 6) a = sigm_(a);
  else if (j == 1) a = softplus_(a);
  const int b = row / N_, n = row % N_;
  outp[(size_t)b * OUTS_ + n * 7 + j] = a;
}

// two-stage deterministic h_global mean
__global__ __launch_bounds__(256) void hglob1_k(const float* __restrict__ h,
                                                float* __restrict__ hgp)
{
  const int b = blockIdx.x;
  const int seg = blockIdx.y;   // 25 segments of 120 nodes
  const int d = threadIdx.x;
  float s = 0.f;
  const int n0 = seg * 120;
  for (int n = n0; n < n0 + 120; ++n)
    s += h[((size_t)(b * N_ + n)) * 256 + d];
  hgp[((size_t)(b * 25 + seg)) * 256 + d] = s;
}

__global__ __launch_bounds__(256) void hglob2_k(const float* __restrict__ hgp,
                                                float* __restrict__ hg)
{
  const int b = blockIdx.x;
  const int d = threadIdx.x;
  float s = 0.f;
  for (int i = 0; i < 25; ++i) s += hgp[((size_t)(b * 25 + i)) * 256 + d];
  hg[b * 256 + d] = s * (1.f / (float)N_);
}

__global__ __launch_bounds__(64) void freq_k(const float* __restrict__ hg,
                                             const float* __restrict__ w1, const float* __restrict__ b1,
                                             const float* __restrict__ w2, const float* __restrict__ b2,
                                             float* __restrict__ outp)
{
  const int b = blockIdx.x;
  const int u = threadIdx.x;
  float a = b1[u];
  for (int k = 0; k < 256; ++k) a += hg[b * 256 + k] * w1[k * 64 + u];
  a = fmaxf(a, 0.f) * w2[u];
  a = wred_(a);
  if (u == 0) outp[(size_t)b * OUTS_ + 45000] = a + b2[0];
}

__global__ void ef_k(const float* __restrict__ h, const int* __restrict__ src,
                     const int* __restrict__ dst, float* __restrict__ ef)
{
  const int idx = blockIdx.x * blockDim.x + threadIdx.x;  // float4 units
  if (idx >= B_ * E_ * 128) return;
  const int q = idx & 127;
  const int row = idx >> 7;
  const int b = row / E_, e = row % E_;
  const int d = q << 2;
  const float* p = (d < 256)
      ? h + ((size_t)(b * N_ + src[e])) * 256 + d
      : h + ((size_t)(b * N_ + dst[e])) * 256 + (d - 256);
  *(float4*)(ef + (size_t)row * 512 + d) = *(const float4*)p;
}

__global__ void eh2_k(const float* __restrict__ hidden, const float* __restrict__ w2,
                      const float* __restrict__ b2, float* __restrict__ outp)
{
  const int idx = blockIdx.x * blockDim.x + threadIdx.x;
  if (idx >= 2 * B_ * E_) return;
  const int jj = idx / (B_ * E_);
  const int r = idx - jj * (B_ * E_);
  const int b = r / E_, e = r % E_;
  const float* hp = hidden + (size_t)r * 128 + jj * 64;
  const float* wp = w2 + jj * 64;
  float a = 0.f;
  #pragma unroll
  for (int u = 0; u < 64; ++u) a += hp[u] * wp[u];
  a += b2[jj];
  outp[(size_t)b * OUTS_ + 21000 + jj * 12000 + e] = a;
}

// ---------------------------------------------------------------------------
extern "C" void kernel_launch(void* const* d_in, const int* in_sizes, int n_in,
                              void* d_out, int out_size, void* d_ws, size_t ws_size,
                              hipStream_t stream)
{
  const float* env      = (const float*)d_in[0];
  const float* infra    = (const float*)d_in[1];
  const float* robot    = (const float*)d_in[2];
  const float* edgeattr = (const float*)d_in[3];
  const int*   eidx     = (const int*)d_in[4];
  const float* wqkv     = (const float*)d_in[5];
  const float* bqkv     = (const float*)d_in[6];
  const float* wo       = (const float*)d_in[7];
  const float* bo       = (const float*)d_in[8];
  const float* lnf_g    = (const float*)d_in[9];
  const float* lnf_b    = (const float*)d_in[10];
  const float* we_emb   = (const float*)d_in[11];
  const float* be_emb   = (const float*)d_in[12];
  const float* tg_W     = (const float*)d_in[13];
  const float* tg_We    = (const float*)d_in[14];
  const float* tg_asrc  = (const float*)d_in[15];
  const float* tg_adst  = (const float*)d_in[16];
  const float* tg_aedge = (const float*)d_in[17];
  const float* w_ih     = (const float*)d_in[18];
  const float* w_hh     = (const float*)d_in[19];
  const float* b_lstm   = (const float*)d_in[20];
  const float* g_W      = (const float*)d_in[21];
  const float* g_We     = (const float*)d_in[22];
  const float* g_asrc   = (const float*)d_in[23];
  const float* g_adst   = (const float*)d_in[24];
  const float* g_aedge  = (const float*)d_in[25];
  const float* g_lng    = (const float*)d_in[26];
  const float* g_lnb    = (const float*)d_in[27];
  const float* hn_w1    = (const float*)d_in[28];
  const float* hn_b1    = (const float*)d_in[29];
  const float* hn_w2    = (const float*)d_in[30];
  const float* hn_b2    = (const float*)d_in[31];
  const float* he_w1    = (const float*)d_in[32];
  const float* he_b1    = (const float*)d_in[33];
  const float* he_w2    = (const float*)d_in[34];
  const float* he_b2    = (const float*)d_in[35];

  const int* src = eidx;
  const int* dst = eidx + E_;
  float* outp = (float*)d_out;
  float* ws = (float*)d_ws;

  // ---- workspace layout (floats), peak ~379.8 MB ----
  const size_t A0 = 24576000;
  float* fseq   = ws;                          // 24,576,000 [dead after xw_all]
  float* gatall = ws;                          // overlays fseq (24,576,000)
  float* efbuf  = ws;                          // overlays gatall at head phase
  // stage A:
  float* qkv   = ws + A0;                      // 27,648,000 (12000 nodes x 2304)
  float* obarA = ws + A0 + 27648000;           // 24,576,000
  float* tmpA  = qkv;                          // reuse
  // stage B:
  float* eemb   = ws + A0;                     // 12,288,000
  float* ewtg   = ws + A0 + 12288000;          // 12,288,000
  float* elogtg = ws + A0 + 24576000;          //    384,000
  float* h      = ws + A0 + 24960000;          //  3,072,000
  float* c      = ws + A0 + 28032000;          //  3,072,000
  float* sal    = ws + A0 + 31104000;          //    768,000
  float* dal    = ws + A0 + 31872000;          //    768,000
  float* xwall  = ws + A0 + 32640000;          // 24,576,000
  float* gates  = ws + A0 + 57216000;          // 12,288,000
  float* hg     = ws + A0 + 69504000;          //      1,024
  float* hgp    = ws + A0 + 69506048;          //     25,600
  int*   ideg   = (int*)(ws + A0 + 69532000);  //  3,008 ints
  int*   iroff  = ideg + 3008;                 //  3,008 ints
  int*   ieord  = iroff + 3008;                // 12,000 ints
  // GAT-layers phase (xwall/gatall dead):
  float* ewl   = xwall;                        // 12,288,000
  float* elogl = xwall + 12288000;             //    384,000
  float* xw_s  = xwall + 12672000;             //  3,072,000
  float* gat_s = xwall + 15744000;             //  3,072,000
  // heads (gates dead):
  float* hidn  = gates;                        //  5,376,000 ([B*N][448])
  float* hide  = gates;                        //  6,144,000 ([B*E][128]) after nh2
  // bf16 transposed weights
  unsigned short* wtb = (unsigned short*)(ws + 94200000);
  unsigned short* wt_qkv = wtb;                // 196,608
  unsigned short* wt_wo  = wtb + 196608;       //  65,536
  unsigned short* wt_tgW = wtb + 262144;       //  65,536
  unsigned short* wt_tgWe= wtb + 327680;       //  65,536
  unsigned short* wt_ih  = wtb + 393216;       // 262,144 ([1024][256])
  unsigned short* wt_hh  = wtb + 655360;       // 262,144 ([1024][256])
  unsigned short* wt_gW  = wtb + 917504;       // 196,608 (3 layers)
  unsigned short* wt_gWe = wtb + 1114112;      // 196,608
  unsigned short* wt_hn  = wtb + 1310720;      // 114,688 (7 heads -> [448][256])
  unsigned short* wt_he  = wtb + 1425408;      //  65,536 (2 heads -> [128][512])

  auto mgemm = [&](const float* A, const unsigned short* Wt, const float* bias,
                   float* C, int M, int N, int K, int lda, int flags,
                   int ldc = 0, int coff = 0,
                   int mDiv = 0, int mOuter = 0, int mOff = 0) {
    dim3 grid(N / 64, (M + 127) / 128);
    gemm_mfma_k<<<grid, dim3(256), 0, stream>>>(A, Wt, bias, C, M, N, K, lda,
                                                ldc ? ldc : N, coff, flags,
                                                mDiv, mOuter, mOff);
  };
  auto cvtb = [&](const float* W, unsigned short* Wt, int K, int N, int L) {
    const int total = K * N * L;
    wtb_k<<<(total + 255) / 256, 256, 0, stream>>>(W, Wt, K, N, total);
  };

  // ---- weight convert+transpose (bf16) ----
  cvtb(wqkv, wt_qkv, 256, 768, 1);
  cvtb(wo, wt_wo, 256, 256, 1);
  cvtb(tg_W, wt_tgW, 256, 256, 1);
  cvtb(tg_We, wt_tgWe, 256, 256, 1);
  cvtb(w_ih, wt_ih, 256, 1024, 1);   // dense [1024][256]
  cvtb(w_hh, wt_hh, 256, 1024, 1);   // dense [1024][256]
  cvtb(g_W, wt_gW, 256, 256, 3);
  cvtb(g_We, wt_gWe, 256, 256, 3);
  cvtb(hn_w1, wt_hn, 256, 64, 7);
  cvtb(he_w1, wt_he, 512, 64, 2);

  // ---- CSR build (deterministic) ----
  hipMemsetAsync(ideg, 0, 3000 * sizeof(int), stream);
  hist_k<<<(E_ + 255) / 256, 256, 0, stream>>>(dst, ideg);
  scan_k<<<1, 256, 0, stream>>>(ideg, iroff);
  fill_k<<<750, 256, 0, stream>>>(dst, iroff, ieord);

  // ---------------- Stage A: token attention -> obar ----------------
  for (int chunk = 0; chunk < 8; ++chunk) {
    const int base = chunk * 12000;  // node rows (b*T+t) flattened
    // qkv[node][slot][768] directly from the 3 source tensors
    mgemm(env + (size_t)base * 256,   wt_qkv, bqkv, qkv, 12000, 768, 256, 256, 0, 2304, 0);
    mgemm(infra + (size_t)base * 256, wt_qkv, bqkv, qkv, 12000, 768, 256, 256, 0, 2304, 768);
    mgemm(robot + (size_t)base * 256, wt_qkv, bqkv, qkv, 12000, 768, 256, 256, 0, 2304, 1536);
    attn_avg_k<<<375, 256, 0, stream>>>(qkv, obarA + (size_t)base * 256, 12000);
  }
  // fused_seq = LN(obar @ wo + bo) over all 96000 rows
  mgemm(obarA, wt_wo, bo, tmpA, 96000, 256, 256, 256, 0);
  ln_k<<<96000, 64, 0, stream>>>(tmpA, lnf_g, lnf_b, fseq);

  // ---------------- Stage B prep ----------------
  {  // edge_emb = relu(edge_attr @ we_emb + be_emb)   (48000 x 256, K=8)
    dim3 grid(4, 750);
    gemm_k<<<grid, dim3(256), 0, stream>>>(edgeattr, we_emb, be_emb, eemb,
                                           48000, 256, 8, 8, 2);
  }
  mgemm(eemb, wt_tgWe, nullptr, ewtg, 48000, 256, 256, 256, 0);
  elog_k<<<1500, 256, 0, stream>>>(ewtg, tg_aedge, elogtg, 48000);

  // time-invariant GAT inputs, batched over all 32 (b,t):
  mgemm(fseq, wt_tgW, nullptr, xwall, 96000, 256, 256, 256, 0);
  alphas_k<<<3000, 256, 0, stream>>>(xwall, tg_asrc, tg_adst, sal, dal, 96000);
  gat_k<<<24000, 256, 0, stream>>>(xwall, ewtg, sal, dal, elogtg, iroff, ieord, src,
                                   gatall, 96000, 3);

  // ---------------- LSTM over T ----------------
  hipMemsetAsync(c, 0, 12288000, stream);
  for (int t = 0; t < T_; ++t) {
    // gates = gat_t @ w_ih + b_lstm (remap rows out of gatall; lda=256!)
    mgemm(gatall, wt_ih, b_lstm, gates, 12000, 1024, 256, 256, 0, 0, 0,
          N_, T_ * N_, t * N_);
    if (t > 0)  // gates += h @ w_hh  (h==0 at t=0)
      mgemm(h, wt_hh, nullptr, gates, 12000, 1024, 256, 256, 1);
    lstm_k<<<12000, 256, 0, stream>>>(gates, h, c);
  }

  // ---------------- 3 GAT layers with residual LN ----------------
  for (int l = 0; l < 3; ++l) {
    mgemm(eemb, wt_gWe + (size_t)l * 65536, nullptr, ewl, 48000, 256, 256, 256, 0);
    elog_k<<<1500, 256, 0, stream>>>(ewl, g_aedge + l * 256, elogl, 48000);
    mgemm(h, wt_gW + (size_t)l * 65536, nullptr, xw_s, 12000, 256, 256, 256, 0);
    alphas_k<<<375, 256, 0, stream>>>(xw_s, g_asrc + l * 256, g_adst + l * 256, sal, dal, 12000);
    gat_k<<<3000, 256, 0, stream>>>(xw_s, ewl, sal, dal, elogl, iroff, ieord, src,
                                    gat_s, 12000, 0);
    resln_k<<<12000, 64, 0, stream>>>(h, gat_s, g_lng + l * 256, g_lnb + l * 256);
  }

  // ---------------- Heads ----------------
  mgemm(h, wt_hn, hn_b1, hidn, 12000, 448, 256, 256, 2);
  nh2_k<<<(84000 + 255) / 256, 256, 0, stream>>>(hidn, hn_w2, hn_b2, outp);

  hglob1_k<<<dim3(4, 25), 256, 0, stream>>>(h, hgp);
  hglob2_k<<<4, 256, 0, stream>>>(hgp, hg);
  freq_k<<<4, 64, 0, stream>>>(hg, hn_w1 + 7 * 16384, hn_b1 + 7 * 64,
                               hn_w2 + 7 * 64, hn_b2 + 7, outp);

  ef_k<<<24000, 256, 0, stream>>>(h, src, dst, efbuf);
  mgemm(efbuf, wt_he, he_b1, hide, 48000, 128, 512, 512, 2);
  eh2_k<<<(96000 + 255) / 256, 256, 0, stream>>>(hide, he_w2, he_b2, outp);
}

// Round 6
// 1914.691 us; speedup vs baseline: 6.9783x; 1.3456x over previous
//
#include <hip/hip_runtime.h>
#include <hip/hip_bf16.h>
#include <math.h>

#define DEV __device__ __forceinline__

namespace {
constexpr int B_ = 4, T_ = 8, N_ = 3000, E_ = 12000;
constexpr int OUTS_ = 45001;  // per-batch output stride: N*7 + E + E + 1
}

using f32x4 = __attribute__((ext_vector_type(4))) float;
using bf16x8 = __attribute__((ext_vector_type(8))) short;

DEV float sigm_(float x) { return 1.0f / (1.0f + expf(-x)); }
DEV float softplus_(float x) { return fmaxf(x, 0.0f) + log1pf(expf(-fabsf(x))); }
DEV float wred_(float v) {
  #pragma unroll
  for (int o = 32; o > 0; o >>= 1) v += __shfl_xor(v, o, 64);
  return v;
}
DEV unsigned short f2bf(float x) {  // RNE fp32->bf16
  unsigned u = __float_as_uint(x);
  return (unsigned short)((u + 0x7FFFu + ((u >> 16) & 1u)) >> 16);
}
DEV unsigned f2bf2(float a, float b) {
  return (unsigned)f2bf(a) | ((unsigned)f2bf(b) << 16);
}
DEV float bfl(unsigned u) { return __uint_as_float(u << 16); }
DEV float bfh(unsigned u) { return __uint_as_float(u & 0xffff0000u); }

// dot of two 32-elem bf16 rows (16B-aligned)
DEV float dot32_(const unsigned short* a, const unsigned short* b)
{
  float s = 0.f;
  #pragma unroll
  for (int i = 0; i < 4; ++i) {
    const uint4 ua = *(const uint4*)(a + i * 8);
    const uint4 ub = *(const uint4*)(b + i * 8);
    const unsigned* pa = &ua.x;
    const unsigned* pb = &ub.x;
    #pragma unroll
    for (int j = 0; j < 4; ++j) {
      s += bfl(pa[j]) * bfl(pb[j]);
      s += bfh(pa[j]) * bfh(pb[j]);
    }
  }
  return s;
}

// ---------------------------------------------------------------------------
// Batched weight transpose+convert: L matrices [K][N] -> per-matrix [N][K] bf16
// ---------------------------------------------------------------------------
__global__ void wtb_k(const float* __restrict__ W, unsigned short* __restrict__ Wt,
                      int K, int N, int total)
{
  const int idx = blockIdx.x * blockDim.x + threadIdx.x;
  if (idx >= total) return;
  const int kn = K * N;
  const int l = idx / kn;
  const int r = idx - l * kn;
  const int k = r / N, n = r - k * N;
  Wt[(size_t)l * kn + (size_t)n * K + k] = f2bf(W[idx]);
}

// env/infra/robot fp32 -> tokb bf16 interleaved [row][slot][256]
__global__ void cvt3_k(const float* __restrict__ env, const float* __restrict__ infra,
                       const float* __restrict__ robot, unsigned short* __restrict__ tokb)
{
  const int total = 96000 * 3 * 32;  // units of 8 elems
  for (int u = blockIdx.x * blockDim.x + threadIdx.x; u < total;
       u += gridDim.x * blockDim.x) {
    const int flat = u * 8;
    const int d = flat & 255;
    const int rs = flat >> 8;
    const int slot = rs % 3;
    const int row = rs / 3;
    const float* sp = (slot == 0 ? env : (slot == 1 ? infra : robot)) + (size_t)row * 256 + d;
    const float4 a = *(const float4*)sp;
    const float4 b = *(const float4*)(sp + 4);
    uint4 o;
    o.x = f2bf2(a.x, a.y); o.y = f2bf2(a.z, a.w);
    o.z = f2bf2(b.x, b.y); o.w = f2bf2(b.z, b.w);
    *(uint4*)(tokb + flat) = o;
  }
}

// ---------------------------------------------------------------------------
// CSR build (deterministic)
// ---------------------------------------------------------------------------
__global__ void hist_k(const int* __restrict__ dst, int* __restrict__ deg)
{
  const int e = blockIdx.x * blockDim.x + threadIdx.x;
  if (e < E_) atomicAdd(&deg[dst[e]], 1);
}

__global__ __launch_bounds__(256) void scan_k(const int* __restrict__ deg,
                                              int* __restrict__ roff)
{
  __shared__ int part[256];
  const int t = threadIdx.x;
  int loc[12];
  int s = 0;
  #pragma unroll
  for (int i = 0; i < 12; ++i) {
    const int n = t * 12 + i;
    loc[i] = s;
    s += (n < N_) ? deg[n] : 0;
  }
  part[t] = s;
  __syncthreads();
  if (t == 0) {
    int run = 0;
    for (int i = 0; i < 256; ++i) { const int v = part[i]; part[i] = run; run += v; }
  }
  __syncthreads();
  const int base = part[t];
  #pragma unroll
  for (int i = 0; i < 12; ++i) {
    const int n = t * 12 + i;
    if (n < N_) roff[n] = base + loc[i];
  }
  if (t == 0) roff[N_] = E_;
}

__global__ __launch_bounds__(256) void fill_k(const int* __restrict__ dst,
                                              const int* __restrict__ roff,
                                              int* __restrict__ eord)
{
  const int n = blockIdx.x * 4 + (threadIdx.x >> 6);
  if (n >= N_) return;
  const int lane = threadIdx.x & 63;
  const unsigned long long ltm = (1ull << lane) - 1ull;
  int cnt = roff[n];
  for (int c = 0; c < E_; c += 64) {
    const int e = c + lane;
    const bool m = (e < E_) && (dst[e] == n);
    const unsigned long long mask = __ballot(m);
    if (m) eord[cnt + __popcll(mask & ltm)] = e;
    cnt += __popcll(mask);
  }
}

// ---------------------------------------------------------------------------
// MFMA bf16 GEMM, bf16 A: C[M,N] = A[M,K](bf16) @ Wt(bf16,[N][K])
// flags: 1 = C += (fp32 C only), 2 = relu, 4 = store bf16 C.
// C index = row*ldc + coff + col (elements of stored type).
// Optional A row remap: phys = (r/mDiv)*mOuter + mOff + r%mDiv
// Tile: 128x64, 4 waves each 64x32 (4x2 frags of 16x16), BK=32.
// ---------------------------------------------------------------------------
__global__ __launch_bounds__(256) void gemm_bfa_k(
    const unsigned short* __restrict__ A, const unsigned short* __restrict__ Wt,
    const float* __restrict__ bias, void* __restrict__ Cv,
    int M, int N, int K, int lda, int ldc, int coff, int flags,
    int mDiv, int mOuter, int mOff)
{
  __shared__ unsigned short Al[128 * 40];
  __shared__ unsigned short Bl[64 * 40];
  const int tid = threadIdx.x;
  const int bm = blockIdx.y * 128;
  const int bn = blockIdx.x * 64;
  const int lane = tid & 63;
  const int wv = tid >> 6;
  const int wm = (wv >> 1) * 64;
  const int wn = (wv & 1) * 32;
  const int s_row = tid >> 1;
  const int s_cb = (tid & 1) * 16;
  const int grow = bm + s_row;
  const unsigned short* Arow = nullptr;
  if (grow < M) {
    int r = grow;
    if (mDiv > 0) r = (r / mDiv) * mOuter + mOff + (r % mDiv);
    Arow = A + (size_t)r * lda;
  }
  const int b_col = tid >> 2;
  const int b_ks = (tid & 3) * 8;
  const unsigned short* Wrow = Wt + (size_t)(bn + b_col) * K + b_ks;

  f32x4 acc[4][2] = {};
  const int l15 = lane & 15;
  const int lk = (lane >> 4) * 8;

  for (int k0 = 0; k0 < K; k0 += 32) {
    uint4 a0, a1;
    if (Arow) {
      a0 = *(const uint4*)(Arow + k0 + s_cb);
      a1 = *(const uint4*)(Arow + k0 + s_cb + 8);
    } else {
      a0 = make_uint4(0, 0, 0, 0);
      a1 = a0;
    }
    *(uint4*)&Al[s_row * 40 + s_cb] = a0;
    *(uint4*)&Al[s_row * 40 + s_cb + 8] = a1;
    *(uint4*)&Bl[b_col * 40 + b_ks] = *(const uint4*)(Wrow + k0);
    __syncthreads();
    bf16x8 af[4], bfr[2];
    #pragma unroll
    for (int m = 0; m < 4; ++m)
      af[m] = *(const bf16x8*)&Al[(wm + m * 16 + l15) * 40 + lk];
    #pragma unroll
    for (int n = 0; n < 2; ++n)
      bfr[n] = *(const bf16x8*)&Bl[(wn + n * 16 + l15) * 40 + lk];
    #pragma unroll
    for (int m = 0; m < 4; ++m)
      #pragma unroll
      for (int n = 0; n < 2; ++n)
        acc[m][n] = __builtin_amdgcn_mfma_f32_16x16x32_bf16(af[m], bfr[n], acc[m][n], 0, 0, 0);
    __syncthreads();
  }
  float* Cf = (float*)Cv;
  unsigned short* Cb = (unsigned short*)Cv;
  const int r4 = (lane >> 4) * 4;
  #pragma unroll
  for (int m = 0; m < 4; ++m) {
    #pragma unroll
    for (int n = 0; n < 2; ++n) {
      const int col = bn + wn + n * 16 + l15;
      const float bv = bias ? bias[col] : 0.f;
      #pragma unroll
      for (int r = 0; r < 4; ++r) {
        const int row = bm + wm + m * 16 + r4 + r;
        if (row >= M) continue;
        float v = acc[m][n][r] + bv;
        const size_t ci = (size_t)row * ldc + coff + col;
        if (flags & 1) v += Cf[ci];
        if (flags & 2) v = fmaxf(v, 0.f);
        if (flags & 4) Cb[ci] = f2bf(v);
        else Cf[ci] = v;
      }
    }
  }
}

// ---------------------------------------------------------------------------
// fp32 fallback GEMM (only the K=8 edge-emb GEMM); flags&4 -> bf16 C store
// ---------------------------------------------------------------------------
__global__ __launch_bounds__(256) void gemm_k(
    const float* __restrict__ A, const float* __restrict__ W,
    const float* __restrict__ bias, void* __restrict__ Cv,
    int M, int N, int K, int lda, int flags)
{
  __shared__ float As[16][68];
  __shared__ float Ws[16][64];
  const int tid = threadIdx.x;
  const int bm = blockIdx.y * 64;
  const int bn = blockIdx.x * 64;
  const int tx = tid & 15;
  const int ty = tid >> 4;
  const int ar = tid >> 2;
  const int ac = (tid & 3) << 2;
  const int wr = tid >> 4;
  const int wc = (tid & 15) << 2;
  const int grow = bm + ar;
  const float* Arow = (grow < M) ? A + (size_t)grow * lda : nullptr;
  float acc[4][4] = {};
  for (int k0 = 0; k0 < K; k0 += 16) {
    float4 av = make_float4(0.f, 0.f, 0.f, 0.f);
    if (Arow) {
      av.x = (k0 + ac + 0 < K) ? Arow[k0 + ac + 0] : 0.f;
      av.y = (k0 + ac + 1 < K) ? Arow[k0 + ac + 1] : 0.f;
      av.z = (k0 + ac + 2 < K) ? Arow[k0 + ac + 2] : 0.f;
      av.w = (k0 + ac + 3 < K) ? Arow[k0 + ac + 3] : 0.f;
    }
    As[ac + 0][ar] = av.x;
    As[ac + 1][ar] = av.y;
    As[ac + 2][ar] = av.z;
    As[ac + 3][ar] = av.w;
    float4 wv = make_float4(0.f, 0.f, 0.f, 0.f);
    if (k0 + wr < K) {
      const int gc = bn + wc;
      const float* wp = W + (size_t)(k0 + wr) * N + gc;
      wv.x = (gc + 0 < N) ? wp[0] : 0.f;
      wv.y = (gc + 1 < N) ? wp[1] : 0.f;
      wv.z = (gc + 2 < N) ? wp[2] : 0.f;
      wv.w = (gc + 3 < N) ? wp[3] : 0.f;
    }
    *(float4*)&Ws[wr][wc] = wv;
    __syncthreads();
    #pragma unroll
    for (int kk = 0; kk < 16; ++kk) {
      const float4 a = *(const float4*)&As[kk][ty << 2];
      const float4 b = *(const float4*)&Ws[kk][tx << 2];
      acc[0][0] += a.x * b.x; acc[0][1] += a.x * b.y; acc[0][2] += a.x * b.z; acc[0][3] += a.x * b.w;
      acc[1][0] += a.y * b.x; acc[1][1] += a.y * b.y; acc[1][2] += a.y * b.z; acc[1][3] += a.y * b.w;
      acc[2][0] += a.z * b.x; acc[2][1] += a.z * b.y; acc[2][2] += a.z * b.z; acc[2][3] += a.z * b.w;
      acc[3][0] += a.w * b.x; acc[3][1] += a.w * b.y; acc[3][2] += a.w * b.z; acc[3][3] += a.w * b.w;
    }
    __syncthreads();
  }
  float* Cf = (float*)Cv;
  unsigned short* Cb = (unsigned short*)Cv;
  #pragma unroll
  for (int i = 0; i < 4; ++i) {
    const int row = bm + (ty << 2) + i;
    if (row >= M) continue;
    #pragma unroll
    for (int j = 0; j < 4; ++j) {
      const int col = bn + (tx << 2) + j;
      if (col >= N) continue;
      float v = acc[i][j];
      if (bias) v += bias[col];
      if (flags & 2) v = fmaxf(v, 0.f);
      const size_t ci = (size_t)row * N + col;
      if (flags & 4) Cb[ci] = f2bf(v);
      else Cf[ci] = v;
    }
  }
}

// ---------------------------------------------------------------------------
// Stage A: per-(node,h) 3x3 attention averaged over query slots. bf16 in/out.
// ---------------------------------------------------------------------------
__global__ void attn_avg_k(const unsigned short* __restrict__ qkv,
                           unsigned short* __restrict__ obar, int nodes)
{
  const int idx = blockIdx.x * blockDim.x + threadIdx.x;
  if (idx >= nodes * 8) return;
  const int node = idx >> 3, h = idx & 7;
  const unsigned short* base = qkv + (size_t)node * 2304 + h * 32;
  float att[3][3];
  #pragma unroll
  for (int s = 0; s < 3; ++s) {
    const unsigned short* q = base + s * 768;
    #pragma unroll
    for (int t = 0; t < 3; ++t) {
      const unsigned short* k = base + t * 768 + 256;
      att[s][t] = dot32_(q, k) * 0.17677669529663687f;
    }
  }
  float cs[3] = {0.f, 0.f, 0.f};
  #pragma unroll
  for (int s = 0; s < 3; ++s) {
    const float m = fmaxf(att[s][0], fmaxf(att[s][1], att[s][2]));
    const float e0 = expf(att[s][0] - m);
    const float e1 = expf(att[s][1] - m);
    const float e2 = expf(att[s][2] - m);
    const float inv = (1.f / 3.f) / (e0 + e1 + e2);
    cs[0] += e0 * inv; cs[1] += e1 * inv; cs[2] += e2 * inv;
  }
  unsigned short* op = obar + (size_t)node * 256 + h * 32;
  #pragma unroll
  for (int i = 0; i < 4; ++i) {  // segments of 8 elems
    const uint4 v0 = *(const uint4*)(base + 0 * 768 + 512 + i * 8);
    const uint4 v1 = *(const uint4*)(base + 1 * 768 + 512 + i * 8);
    const uint4 v2 = *(const uint4*)(base + 2 * 768 + 512 + i * 8);
    const unsigned* p0 = &v0.x;
    const unsigned* p1 = &v1.x;
    const unsigned* p2 = &v2.x;
    uint4 ou;
    unsigned* po = &ou.x;
    #pragma unroll
    for (int j = 0; j < 4; ++j) {
      const float lo = cs[0] * bfl(p0[j]) + cs[1] * bfl(p1[j]) + cs[2] * bfl(p2[j]);
      const float hi = cs[0] * bfh(p0[j]) + cs[1] * bfh(p1[j]) + cs[2] * bfh(p2[j]);
      po[j] = f2bf2(lo, hi);
    }
    *(uint4*)(op + i * 8) = ou;
  }
}

// LayerNorm per row; fp32 in, bf16 out. 1 wave per row.
__global__ __launch_bounds__(64) void ln_k(
    const float* __restrict__ in, const float* __restrict__ g,
    const float* __restrict__ bta, unsigned short* __restrict__ outp)
{
  const int row = blockIdx.x;
  const int d0 = threadIdx.x << 2;
  const float4 a = *(const float4*)(in + (size_t)row * 256 + d0);
  float x[4] = { a.x, a.y, a.z, a.w };
  float s = x[0] + x[1] + x[2] + x[3];
  s = wred_(s);
  const float mean = s * (1.f / 256.f);
  float vs = 0.f;
  #pragma unroll
  for (int i = 0; i < 4; ++i) { const float dd = x[i] - mean; vs += dd * dd; }
  vs = wred_(vs);
  const float inv = 1.0f / sqrtf(vs * (1.f / 256.f) + 1e-5f);
  const float4 gv = *(const float4*)(g + d0);
  const float4 bv = *(const float4*)(bta + d0);
  uint2 o;
  o.x = f2bf2((x[0] - mean) * inv * gv.x + bv.x, (x[1] - mean) * inv * gv.y + bv.y);
  o.y = f2bf2((x[2] - mean) * inv * gv.z + bv.z, (x[3] - mean) * inv * gv.w + bv.w);
  *(uint2*)(outp + (size_t)row * 256 + d0) = o;
}

// ---------------------------------------------------------------------------
// GAT kernels (bf16 feature inputs)
// ---------------------------------------------------------------------------
__global__ void alphas_k(const unsigned short* __restrict__ xw, const float* __restrict__ as,
                         const float* __restrict__ ad, float* __restrict__ sal,
                         float* __restrict__ dal, int rows)
{
  const int idx = blockIdx.x * blockDim.x + threadIdx.x;
  if (idx >= rows * 8) return;
  const int row = idx >> 3, h = idx & 7;
  const unsigned short* x = xw + (size_t)row * 256 + h * 32;
  const float* a1 = as + h * 32;
  const float* a2 = ad + h * 32;
  float s = 0.f, d = 0.f;
  #pragma unroll
  for (int i = 0; i < 4; ++i) {
    const uint4 ux = *(const uint4*)(x + i * 8);
    const unsigned* p = &ux.x;
    #pragma unroll
    for (int j = 0; j < 4; ++j) {
      const float lo = bfl(p[j]), hi = bfh(p[j]);
      s += lo * a1[i * 8 + 2 * j] + hi * a1[i * 8 + 2 * j + 1];
      d += lo * a2[i * 8 + 2 * j] + hi * a2[i * 8 + 2 * j + 1];
    }
  }
  sal[idx] = s; dal[idx] = d;
}

__global__ void elog_k(const unsigned short* __restrict__ ew, const float* __restrict__ ae,
                       float* __restrict__ el, int rows)
{
  const int idx = blockIdx.x * blockDim.x + threadIdx.x;
  if (idx >= rows * 8) return;
  const int row = idx >> 3, h = idx & 7;
  const unsigned short* x = ew + (size_t)row * 256 + h * 32;
  const float* a1 = ae + h * 32;
  float s = 0.f;
  #pragma unroll
  for (int i = 0; i < 4; ++i) {
    const uint4 ux = *(const uint4*)(x + i * 8);
    const unsigned* p = &ux.x;
    #pragma unroll
    for (int j = 0; j < 4; ++j) {
      s += bfl(p[j]) * a1[i * 8 + 2 * j] + bfh(p[j]) * a1[i * 8 + 2 * j + 1];
    }
  }
  el[idx] = s;
}

// Fused GAT aggregation: one wave per (beta,node). Online softmax over incoming
// edges (CSR). bf16 gathers. OUTBF: 1 -> bf16 out, 0 -> fp32 out.
template<int OUTBF>
__global__ __launch_bounds__(256) void gat_k(
    const unsigned short* __restrict__ xw, const unsigned short* __restrict__ ew,
    const float* __restrict__ sal, const float* __restrict__ dal,
    const float* __restrict__ el, const int* __restrict__ roff,
    const int* __restrict__ eord, const int* __restrict__ srcArr,
    void* __restrict__ outp, int nwaves, int tshift)
{
  const int wid = blockIdx.x * 4 + (threadIdx.x >> 6);
  if (wid >= nwaves) return;
  const int beta = wid / N_;
  const int n = wid - beta * N_;
  const int b = beta >> tshift;
  const int lane = threadIdx.x & 63;
  const int h = lane >> 3;
  const int d0 = lane << 2;
  const float dal_h = dal[(size_t)wid * 8 + h];
  const int p0 = roff[n], p1 = roff[n + 1];
  float m = -1e30f, s = 0.f;
  float4 acc = make_float4(0.f, 0.f, 0.f, 0.f);
  for (int p = p0; p < p1; ++p) {
    const int e = eord[p];
    const int sc = srcArr[e];
    float lg = sal[((size_t)beta * N_ + sc) * 8 + h] + dal_h + el[((size_t)b * E_ + e) * 8 + h];
    lg = lg > 0.f ? lg : 0.2f * lg;
    const float mn = fmaxf(m, lg);
    const float scale = expf(m - mn);
    const float w = expf(lg - mn);
    s = s * scale + w;
    const uint2 ux = *(const uint2*)(xw + ((size_t)beta * N_ + sc) * 256 + d0);
    const uint2 ue = *(const uint2*)(ew + ((size_t)b * E_ + e) * 256 + d0);
    acc.x = acc.x * scale + w * (bfl(ux.x) + bfl(ue.x));
    acc.y = acc.y * scale + w * (bfh(ux.x) + bfh(ue.x));
    acc.z = acc.z * scale + w * (bfl(ux.y) + bfl(ue.y));
    acc.w = acc.w * scale + w * (bfh(ux.y) + bfh(ue.y));
    m = mn;
  }
  const float inv = 1.0f / (s + 1e-16f);
  if (OUTBF) {
    uint2 o;
    o.x = f2bf2(acc.x * inv, acc.y * inv);
    o.y = f2bf2(acc.z * inv, acc.w * inv);
    *(uint2*)((unsigned short*)outp + (size_t)wid * 256 + d0) = o;
  } else {
    *(float4*)((float*)outp + (size_t)wid * 256 + d0) =
        make_float4(acc.x * inv, acc.y * inv, acc.z * inv, acc.w * inv);
  }
}

// LSTM cell pointwise; writes fp32 h and bf16 hb
__global__ __launch_bounds__(256) void lstm_k(const float* __restrict__ gates,
                                              float* __restrict__ h, float* __restrict__ c,
                                              unsigned short* __restrict__ hb)
{
  const int row = blockIdx.x;
  const int d = threadIdx.x;
  const float* g = gates + (size_t)row * 1024;
  const float i_ = sigm_(g[d]);
  const float f_ = sigm_(g[256 + d]);
  const float gg = tanhf(g[512 + d]);
  const float o_ = sigm_(g[768 + d]);
  const size_t idx = (size_t)row * 256 + d;
  const float cn = f_ * c[idx] + i_ * gg;
  c[idx] = cn;
  const float hn = o_ * tanhf(cn);
  h[idx] = hn;
  hb[idx] = f2bf(hn);
}

// h = LN(h + add); writes fp32 h and bf16 hb
__global__ __launch_bounds__(64) void resln_k(float* __restrict__ h,
                                              const float* __restrict__ add,
                                              const float* __restrict__ g,
                                              const float* __restrict__ bta,
                                              unsigned short* __restrict__ hb)
{
  const int row = blockIdx.x;
  const int d0 = threadIdx.x << 2;
  float* hp = h + (size_t)row * 256;
  const float4 hv = *(const float4*)(hp + d0);
  const float4 av = *(const float4*)(add + (size_t)row * 256 + d0);
  float x[4] = { hv.x + av.x, hv.y + av.y, hv.z + av.z, hv.w + av.w };
  float s = x[0] + x[1] + x[2] + x[3];
  s = wred_(s);
  const float mean = s * (1.f / 256.f);
  float vs = 0.f;
  #pragma unroll
  for (int i = 0; i < 4; ++i) { const float dd = x[i] - mean; vs += dd * dd; }
  vs = wred_(vs);
  const float inv = 1.0f / sqrtf(vs * (1.f / 256.f) + 1e-5f);
  const float4 gv = *(const float4*)(g + d0);
  const float4 bv = *(const float4*)(bta + d0);
  float o0 = (x[0] - mean) * inv * gv.x + bv.x;
  float o1 = (x[1] - mean) * inv * gv.y + bv.y;
  float o2 = (x[2] - mean) * inv * gv.z + bv.z;
  float o3 = (x[3] - mean) * inv * gv.w + bv.w;
  *(float4*)(hp + d0) = make_float4(o0, o1, o2, o3);
  uint2 ob;
  ob.x = f2bf2(o0, o1);
  ob.y = f2bf2(o2, o3);
  *(uint2*)(hb + (size_t)row * 256 + d0) = ob;
}

// ---------------------------------------------------------------------------
// Head kernels
// ---------------------------------------------------------------------------
__global__ void nh2_k(const float* __restrict__ hidden, const float* __restrict__ w2,
                      const float* __restrict__ b2, float* __restrict__ outp)
{
  const int idx = blockIdx.x * blockDim.x + threadIdx.x;
  if (idx >= B_ * N_ * 7) return;
  const int row = idx / 7, j = idx % 7;
  const float* hp = hidden + (size_t)row * 448 + j * 64;
  const float* wp = w2 + j * 64;
  float a = 0.f;
  #pragma unroll
  for (int u = 0; u < 64; ++u) a += hp[u] * wp[u];
  a += b2[j];
  if (j == 0 || j == 6) a = sigm_(a);
  else if (j == 1) a = softplus_(a);
  const int b = row / N_, n = row % N_;
  outp[(size_t)b * OUTS_ + n * 7 + j] = a;
}

// two-stage deterministic h_global mean
__global__ __launch_bounds__(256) void hglob1_k(const float* __restrict__ h,
                                                float* __restrict__ hgp)
{
  const int b = blockIdx.x;
  const int seg = blockIdx.y;
  const int d = threadIdx.x;
  float s = 0.f;
  const int n0 = seg * 120;
  for (int n = n0; n < n0 + 120; ++n)
    s += h[((size_t)(b * N_ + n)) * 256 + d];
  hgp[((size_t)(b * 25 + seg)) * 256 + d] = s;
}

__global__ __launch_bounds__(256) void hglob2_k(const float* __restrict__ hgp,
                                                float* __restrict__ hg)
{
  const int b = blockIdx.x;
  const int d = threadIdx.x;
  float s = 0.f;
  for (int i = 0; i < 25; ++i) s += hgp[((size_t)(b * 25 + i)) * 256 + d];
  hg[b * 256 + d] = s * (1.f / (float)N_);
}

__global__ __launch_bounds__(64) void freq_k(const float* __restrict__ hg,
                                             const float* __restrict__ w1, const float* __restrict__ b1,
                                             const float* __restrict__ w2, const float* __restrict__ b2,
                                             float* __restrict__ outp)
{
  const int b = blockIdx.x;
  const int u = threadIdx.x;
  float a = b1[u];
  for (int k = 0; k < 256; ++k) a += hg[b * 256 + k] * w1[k * 64 + u];
  a = fmaxf(a, 0.f) * w2[u];
  a = wred_(a);
  if (u == 0) outp[(size_t)b * OUTS_ + 45000] = a + b2[0];
}

// gather ef = [hb[b,src], hb[b,dst]] bf16 (B*E x 512)
__global__ void ef_k(const unsigned short* __restrict__ hb, const int* __restrict__ src,
                     const int* __restrict__ dst, unsigned short* __restrict__ ef)
{
  const int idx = blockIdx.x * blockDim.x + threadIdx.x;  // units of 8 elems
  if (idx >= B_ * E_ * 64) return;
  const int q = idx & 63;
  const int row = idx >> 6;
  const int b = row / E_, e = row % E_;
  const int d = q << 3;
  const unsigned short* p = (d < 256)
      ? hb + ((size_t)(b * N_ + src[e])) * 256 + d
      : hb + ((size_t)(b * N_ + dst[e])) * 256 + (d - 256);
  *(uint4*)(ef + (size_t)row * 512 + d) = *(const uint4*)p;
}

__global__ void eh2_k(const float* __restrict__ hidden, const float* __restrict__ w2,
                      const float* __restrict__ b2, float* __restrict__ outp)
{
  const int idx = blockIdx.x * blockDim.x + threadIdx.x;
  if (idx >= 2 * B_ * E_) return;
  const int jj = idx / (B_ * E_);
  const int r = idx - jj * (B_ * E_);
  const int b = r / E_, e = r % E_;
  const float* hp = hidden + (size_t)r * 128 + jj * 64;
  const float* wp = w2 + jj * 64;
  float a = 0.f;
  #pragma unroll
  for (int u = 0; u < 64; ++u) a += hp[u] * wp[u];
  a += b2[jj];
  outp[(size_t)b * OUTS_ + 21000 + jj * 12000 + e] = a;
}

// ---------------------------------------------------------------------------
extern "C" void kernel_launch(void* const* d_in, const int* in_sizes, int n_in,
                              void* d_out, int out_size, void* d_ws, size_t ws_size,
                              hipStream_t stream)
{
  const float* env      = (const float*)d_in[0];
  const float* infra    = (const float*)d_in[1];
  const float* robot    = (const float*)d_in[2];
  const float* edgeattr = (const float*)d_in[3];
  const int*   eidx     = (const int*)d_in[4];
  const float* wqkv     = (const float*)d_in[5];
  const float* bqkv     = (const float*)d_in[6];
  const float* wo       = (const float*)d_in[7];
  const float* bo       = (const float*)d_in[8];
  const float* lnf_g    = (const float*)d_in[9];
  const float* lnf_b    = (const float*)d_in[10];
  const float* we_emb   = (const float*)d_in[11];
  const float* be_emb   = (const float*)d_in[12];
  const float* tg_W     = (const float*)d_in[13];
  const float* tg_We    = (const float*)d_in[14];
  const float* tg_asrc  = (const float*)d_in[15];
  const float* tg_adst  = (const float*)d_in[16];
  const float* tg_aedge = (const float*)d_in[17];
  const float* w_ih     = (const float*)d_in[18];
  const float* w_hh     = (const float*)d_in[19];
  const float* b_lstm   = (const float*)d_in[20];
  const float* g_W      = (const float*)d_in[21];
  const float* g_We     = (const float*)d_in[22];
  const float* g_asrc   = (const float*)d_in[23];
  const float* g_adst   = (const float*)d_in[24];
  const float* g_aedge  = (const float*)d_in[25];
  const float* g_lng    = (const float*)d_in[26];
  const float* g_lnb    = (const float*)d_in[27];
  const float* hn_w1    = (const float*)d_in[28];
  const float* hn_b1    = (const float*)d_in[29];
  const float* hn_w2    = (const float*)d_in[30];
  const float* hn_b2    = (const float*)d_in[31];
  const float* he_w1    = (const float*)d_in[32];
  const float* he_b1    = (const float*)d_in[33];
  const float* he_w2    = (const float*)d_in[34];
  const float* he_b2    = (const float*)d_in[35];

  const int* src = eidx;
  const int* dst = eidx + E_;
  float* outp = (float*)d_out;
  float* ws = (float*)d_ws;

  // ---- bf16 transposed weights at ws start (~3 MB) ----
  unsigned short* wtb0 = (unsigned short*)ws;
  unsigned short* wt_qkv = wtb0;               // 196,608
  unsigned short* wt_wo  = wtb0 + 196608;      //  65,536
  unsigned short* wt_tgW = wtb0 + 262144;      //  65,536
  unsigned short* wt_tgWe= wtb0 + 327680;      //  65,536
  unsigned short* wt_ih  = wtb0 + 393216;      // 262,144
  unsigned short* wt_hh  = wtb0 + 655360;      // 262,144
  unsigned short* wt_gW  = wtb0 + 917504;      // 196,608 (3 layers)
  unsigned short* wt_gWe = wtb0 + 1114112;     // 196,608
  unsigned short* wt_hn  = wtb0 + 1310720;     // 114,688
  unsigned short* wt_he  = wtb0 + 1425408;     //  65,536

  // ---- dynamic regions (float-unit offsets from D0; peak ~308 MB) ----
  const size_t D0 = 1600000;
  // stage A:
  unsigned short* tokb  = (unsigned short*)(ws + D0);              // 36.86M f
  unsigned short* qkvb  = (unsigned short*)(ws + D0 + 36864000);   // 13.82M f
  unsigned short* obarb = (unsigned short*)(ws + D0 + 50688000);   // 12.29M f
  unsigned short* fseqb = (unsigned short*)(ws + D0 + 62976000);   // 12.29M f
  float* tmpA = ws + D0;                                           // 24.58M f (over tokb)
  // stage B:
  unsigned short* xwallb  = (unsigned short*)(ws + D0);            // 12.29M f
  unsigned short* gatallb = (unsigned short*)(ws + D0 + 12288000); // 12.29M f
  unsigned short* eembb   = (unsigned short*)(ws + D0 + 24576000); //  6.14M f
  unsigned short* ewtgb   = (unsigned short*)(ws + D0 + 30720000); //  6.14M f
  float* elogtg = ws + D0 + 36864000;          //    384,000
  float* sal    = ws + D0 + 37248000;          //    768,000
  float* dal    = ws + D0 + 38016000;          //    768,000
  float* h      = ws + D0 + 38784000;          //  3,072,000
  unsigned short* hb = (unsigned short*)(ws + D0 + 41856000);      // 1.54M f
  float* c      = ws + D0 + 43392000;          //  3,072,000
  float* gates  = ws + D0 + 46464000;          // 12,288,000
  // GAT-layers phase (xwall/gatall dead):
  unsigned short* ewlb  = (unsigned short*)(ws + D0);              // 6.14M f
  float* elogl = ws + D0 + 6144000;            //    384,000
  unsigned short* xw_sb = (unsigned short*)(ws + D0 + 6528000);    // 1.54M f
  float* gat_s = ws + D0 + 8064000;            //  3,072,000
  // heads:
  float* hidn  = gates;                        //  5,376,000
  unsigned short* efb = (unsigned short*)(ws + D0 + 12288000);     // 12.29M f
  float* hide  = ws + D0 + 52000000;           //  6,144,000
  // CSR + small (beyond fseq end, D0+75,264,000):
  int* ideg  = (int*)(ws + D0 + 75264000);
  int* iroff = ideg + 3008;
  int* ieord = iroff + 3008;
  float* hg  = ws + D0 + 75280000;
  float* hgp = ws + D0 + 75282048;

  auto mgemm = [&](const unsigned short* A, const unsigned short* Wt, const float* bias,
                   void* C, int M, int N, int K, int lda, int flags,
                   int ldc = 0, int coff = 0,
                   int mDiv = 0, int mOuter = 0, int mOff = 0) {
    dim3 grid(N / 64, (M + 127) / 128);
    gemm_bfa_k<<<grid, dim3(256), 0, stream>>>(A, Wt, bias, C, M, N, K, lda,
                                               ldc ? ldc : N, coff, flags,
                                               mDiv, mOuter, mOff);
  };
  auto cvtb = [&](const float* W, unsigned short* Wt, int K, int N, int L) {
    const int total = K * N * L;
    wtb_k<<<(total + 255) / 256, 256, 0, stream>>>(W, Wt, K, N, total);
  };

  // ---- weight convert+transpose ----
  cvtb(wqkv, wt_qkv, 256, 768, 1);
  cvtb(wo, wt_wo, 256, 256, 1);
  cvtb(tg_W, wt_tgW, 256, 256, 1);
  cvtb(tg_We, wt_tgWe, 256, 256, 1);
  cvtb(w_ih, wt_ih, 256, 1024, 1);
  cvtb(w_hh, wt_hh, 256, 1024, 1);
  cvtb(g_W, wt_gW, 256, 256, 3);
  cvtb(g_We, wt_gWe, 256, 256, 3);
  cvtb(hn_w1, wt_hn, 256, 64, 7);
  cvtb(he_w1, wt_he, 512, 64, 2);

  // ---- CSR build (deterministic) ----
  hipMemsetAsync(ideg, 0, 3000 * sizeof(int), stream);
  hist_k<<<(E_ + 255) / 256, 256, 0, stream>>>(dst, ideg);
  scan_k<<<1, 256, 0, stream>>>(ideg, iroff);
  fill_k<<<750, 256, 0, stream>>>(dst, iroff, ieord);

  // ---------------- Stage A ----------------
  cvt3_k<<<2048, 256, 0, stream>>>(env, infra, robot, tokb);
  for (int chunk = 0; chunk < 8; ++chunk) {
    mgemm(tokb + (size_t)chunk * 36000 * 256, wt_qkv, bqkv, qkvb,
          36000, 768, 256, 256, 4);
    attn_avg_k<<<375, 256, 0, stream>>>(qkvb, obarb + (size_t)chunk * 12000 * 256, 12000);
  }
  // tmpA = obar @ wo + bo (fp32), then fseq = LN(tmpA) (bf16)
  mgemm(obarb, wt_wo, bo, tmpA, 96000, 256, 256, 256, 0);
  ln_k<<<96000, 64, 0, stream>>>(tmpA, lnf_g, lnf_b, fseqb);

  // ---------------- Stage B prep ----------------
  {  // edge_emb = relu(edge_attr @ we_emb + be_emb) -> bf16
    dim3 grid(4, 750);
    gemm_k<<<grid, dim3(256), 0, stream>>>(edgeattr, we_emb, be_emb, eembb,
                                           48000, 256, 8, 8, 2 | 4);
  }
  mgemm(eembb, wt_tgWe, nullptr, ewtgb, 48000, 256, 256, 256, 4);
  elog_k<<<1500, 256, 0, stream>>>(ewtgb, tg_aedge, elogtg, 48000);

  mgemm(fseqb, wt_tgW, nullptr, xwallb, 96000, 256, 256, 256, 4);
  alphas_k<<<3000, 256, 0, stream>>>(xwallb, tg_asrc, tg_adst, sal, dal, 96000);
  gat_k<1><<<24000, 256, 0, stream>>>(xwallb, ewtgb, sal, dal, elogtg, iroff, ieord,
                                      src, gatallb, 96000, 3);

  // ---------------- LSTM over T ----------------
  hipMemsetAsync(c, 0, 12288000, stream);
  for (int t = 0; t < T_; ++t) {
    mgemm(gatallb, wt_ih, b_lstm, gates, 12000, 1024, 256, 256, 0, 0, 0,
          N_, T_ * N_, t * N_);
    if (t > 0)
      mgemm(hb, wt_hh, nullptr, gates, 12000, 1024, 256, 256, 1);
    lstm_k<<<12000, 256, 0, stream>>>(gates, h, c, hb);
  }

  // ---------------- 3 GAT layers with residual LN ----------------
  for (int l = 0; l < 3; ++l) {
    mgemm(eembb, wt_gWe + (size_t)l * 65536, nullptr, ewlb, 48000, 256, 256, 256, 4);
    elog_k<<<1500, 256, 0, stream>>>(ewlb, g_aedge + l * 256, elogl, 48000);
    mgemm(hb, wt_gW + (size_t)l * 65536, nullptr, xw_sb, 12000, 256, 256, 256, 4);
    alphas_k<<<375, 256, 0, stream>>>(xw_sb, g_asrc + l * 256, g_adst + l * 256, sal, dal, 12000);
    gat_k<0><<<3000, 256, 0, stream>>>(xw_sb, ewlb, sal, dal, elogl, iroff, ieord,
                                       src, gat_s, 12000, 0);
    resln_k<<<12000, 64, 0, stream>>>(h, gat_s, g_lng + l * 256, g_lnb + l * 256, hb);
  }

  // ---------------- Heads ----------------
  mgemm(hb, wt_hn, hn_b1, hidn, 12000, 448, 256, 256, 2);
  nh2_k<<<(84000 + 255) / 256, 256, 0, stream>>>(hidn, hn_w2, hn_b2, outp);

  hglob1_k<<<dim3(4, 25), 256, 0, stream>>>(h, hgp);
  hglob2_k<<<4, 256, 0, stream>>>(hgp, hg);
  freq_k<<<4, 64, 0, stream>>>(hg, hn_w1 + 7 * 16384, hn_b1 + 7 * 64,
                               hn_w2 + 7 * 64, hn_b2 + 7, outp);

  ef_k<<<12000, 256, 0, stream>>>(hb, src, dst, efb);
  mgemm(efb, wt_he, he_b1, hide, 48000, 128, 512, 512, 2);
  eh2_k<<<(96000 + 255) / 256, 256, 0, stream>>>(hide, he_w2, he_b2, outp);
}